// Round 1
// baseline (1054.218 us; speedup 1.0000x reference)
//
#include <hip/hip_runtime.h>
#include <stdint.h>

#define N_USER_C  50000
#define N_ITEM_C  100000
#define N_NODES_C 150000
#define EMB_C     64
#define NNZ_C     1200000
#define BATCH_C   4096

// ---------------- edge weights with sparse dropout ----------------
__global__ __launch_bounds__(256) void k_vals(const float* __restrict__ av,
                                              const float* __restrict__ du,
                                              float* __restrict__ vals) {
    int i = blockIdx.x * blockDim.x + threadIdx.x;
    if (i < NNZ_C) {
        float m = floorf(0.9f + du[i]);            // 0/1 keep mask, matches jnp.floor
        vals[i] = av[i] * m * (float)(1.0 / 0.9);  // rescale by 1/(1-rate)
    }
}

// ---------------- ego0 = concat(user_emb, item_emb) ----------------
__global__ __launch_bounds__(256) void k_concat(const float* __restrict__ ue,
                                                const float* __restrict__ ie,
                                                float* __restrict__ ego) {
    const int64_t totalU = (int64_t)N_USER_C * EMB_C / 4;
    const int64_t total  = (int64_t)N_NODES_C * EMB_C / 4;
    int64_t stride = (int64_t)gridDim.x * blockDim.x;
    for (int64_t i = (int64_t)blockIdx.x * blockDim.x + threadIdx.x; i < total; i += stride) {
        float4 v = (i < totalU) ? ((const float4*)ue)[i] : ((const float4*)ie)[i - totalU];
        ((float4*)ego)[i] = v;
    }
}

// ---------------- SpMM: next[r] += v * ego[c], one wave per edge ----------------
__global__ __launch_bounds__(256) void k_spmm(const float* __restrict__ vals,
                                              const int* __restrict__ rows,
                                              const int* __restrict__ cols,
                                              const float* __restrict__ ego,
                                              float* __restrict__ nxt) {
    int t = blockIdx.x * blockDim.x + threadIdx.x;
    int d = t & 63;
    int e = t >> 6;                                   // wave-uniform edge id
    int estride = (gridDim.x * blockDim.x) >> 6;
    for (; e < NNZ_C; e += estride) {
        float v = vals[e];                            // wave-uniform -> scalarized
        if (v != 0.0f) {
            int c = cols[e];
            int r = rows[e];
            float x = v * ego[(int64_t)c * EMB_C + d];   // 256B coalesced gather
            atomicAdd(&nxt[(int64_t)r * EMB_C + d], x);  // 256B contiguous atomics
        }
    }
}

// ---------------- gather-accumulate the batch rows for hop `hop` ----------------
__global__ __launch_bounds__(256) void k_gather(const float* __restrict__ src,
                                                float* __restrict__ out,
                                                const int* __restrict__ users,
                                                const int* __restrict__ pos,
                                                const int* __restrict__ neg,
                                                const int* __restrict__ ua,
                                                const int* __restrict__ pa,
                                                const int* __restrict__ na,
                                                const int* __restrict__ indexp,
                                                int hop, int init) {
    int t = blockIdx.x * blockDim.x + threadIdx.x;
    if (t >= 3 * BATCH_C * EMB_C) return;
    int d = t & 63;
    int b = t >> 6;            // 0 .. 3*BATCH-1
    int s = b >> 12;           // 0=u, 1=p, 2=n   (BATCH=4096)
    int j = b & (BATCH_C - 1);
    int idx0 = indexp[0];
    int row, a;
    if (s == 0)      { row = users[j] + (idx0 ? N_USER_C : 0); a = ua[j]; }
    else if (s == 1) { row = pos[j]   + (idx0 ? 0 : N_USER_C); a = pa[j]; }
    else             { row = neg[j]   + (idx0 ? 0 : N_USER_C); a = na[j]; }
    if (hop <= a) {
        float x = src[(int64_t)row * EMB_C + d];
        if (init) out[t] = x;
        else      out[t] += x;
    } else if (init) {
        out[t] = 0.0f;   // unreachable for hop 0 (a >= 0), kept for safety
    }
}

// ---------------- divide by (a+1) ----------------
__global__ __launch_bounds__(256) void k_scale(float* __restrict__ out,
                                               const int* __restrict__ ua,
                                               const int* __restrict__ pa,
                                               const int* __restrict__ na) {
    int t = blockIdx.x * blockDim.x + threadIdx.x;
    if (t >= 3 * BATCH_C * EMB_C) return;
    int b = t >> 6;
    int s = b >> 12;
    int j = b & (BATCH_C - 1);
    int a = (s == 0) ? ua[j] : (s == 1) ? pa[j] : na[j];
    out[t] /= (float)(a + 1);
}

extern "C" void kernel_launch(void* const* d_in, const int* in_sizes, int n_in,
                              void* d_out, int out_size, void* d_ws, size_t ws_size,
                              hipStream_t stream) {
    const float* user_emb = (const float*)d_in[0];
    const float* item_emb = (const float*)d_in[1];
    const float* adj_vals = (const float*)d_in[2];
    const float* drop_u   = (const float*)d_in[3];
    const int*   adj_rows = (const int*)d_in[4];
    const int*   adj_cols = (const int*)d_in[5];
    const int*   users    = (const int*)d_in[6];
    const int*   pos_it   = (const int*)d_in[7];
    const int*   neg_it   = (const int*)d_in[8];
    const int*   u_a      = (const int*)d_in[9];
    const int*   p_a      = (const int*)d_in[10];
    const int*   n_a      = (const int*)d_in[11];
    const int*   indexp   = (const int*)d_in[12];
    float* out = (float*)d_out;

    // workspace layout (floats)
    const size_t egoElems = (size_t)N_NODES_C * EMB_C;   // 9.6M floats
    float* bufA = (float*)d_ws;
    float* bufB = bufA + egoElems;
    float* vals = bufB + egoElems;

    // 1. edge weights
    k_vals<<<(NNZ_C + 255) / 256, 256, 0, stream>>>(adj_vals, drop_u, vals);
    // 2. ego0
    k_concat<<<2048, 256, 0, stream>>>(user_emb, item_emb, bufA);
    // 3. hop-0 gather (init)
    const int GT = 3 * BATCH_C * EMB_C;
    k_gather<<<(GT + 255) / 256, 256, 0, stream>>>(bufA, out, users, pos_it, neg_it,
                                                   u_a, p_a, n_a, indexp, 0, 1);
    // 4. four SpMM hops with incremental gather
    float* cur = bufA;
    float* nxt = bufB;
    for (int hop = 1; hop <= 4; ++hop) {
        hipMemsetAsync(nxt, 0, egoElems * sizeof(float), stream);
        k_spmm<<<2048, 256, 0, stream>>>(vals, adj_rows, adj_cols, cur, nxt);
        k_gather<<<(GT + 255) / 256, 256, 0, stream>>>(nxt, out, users, pos_it, neg_it,
                                                       u_a, p_a, n_a, indexp, hop, 0);
        float* tmp = cur; cur = nxt; nxt = tmp;
    }
    // 5. final divide by (a+1)
    k_scale<<<(GT + 255) / 256, 256, 0, stream>>>(out, u_a, p_a, n_a);
}

// Round 2
// 780.930 us; speedup vs baseline: 1.3500x; 1.3500x over previous
//
#include <hip/hip_runtime.h>
#include <stdint.h>

#define N_USER_C  50000
#define N_ITEM_C  100000
#define N_NODES_C 150000
#define EMB_C     64
#define NNZ_C     1200000
#define BATCH_C   4096
#define SCAN_T    1024

// ---------------- histogram of kept-edge rows ----------------
__global__ __launch_bounds__(256) void k_hist(const float* __restrict__ du,
                                              const int* __restrict__ rows,
                                              int* __restrict__ cnt) {
    int i = blockIdx.x * blockDim.x + threadIdx.x;
    if (i < NNZ_C) {
        float m = floorf(0.9f + du[i]);      // 0/1 keep mask, matches jnp.floor
        if (m != 0.0f) atomicAdd(&cnt[rows[i]], 1);
    }
}

// ---------------- single-block exclusive scan over 150k counts ----------------
__global__ __launch_bounds__(SCAN_T) void k_scan(const int* __restrict__ cnt,
                                                 int* __restrict__ row_start,
                                                 int* __restrict__ row_cursor) {
    __shared__ int partial[SCAN_T];
    const int tid = threadIdx.x;
    const int chunk = (N_NODES_C + SCAN_T - 1) / SCAN_T;
    const int base = tid * chunk;
    int s = 0;
    for (int i = 0; i < chunk; ++i) {
        int idx = base + i;
        if (idx < N_NODES_C) s += cnt[idx];
    }
    partial[tid] = s;
    __syncthreads();
    for (int off = 1; off < SCAN_T; off <<= 1) {   // Hillis-Steele inclusive scan
        int v = (tid >= off) ? partial[tid - off] : 0;
        __syncthreads();
        partial[tid] += v;
        __syncthreads();
    }
    int run = partial[tid] - s;                     // exclusive prefix for this chunk
    for (int i = 0; i < chunk; ++i) {
        int idx = base + i;
        if (idx < N_NODES_C) {
            row_start[idx]  = run;
            row_cursor[idx] = run;
            run += cnt[idx];
        }
    }
}

// ---------------- scatter kept edges into row-sorted (col,val) payload ----------------
__global__ __launch_bounds__(256) void k_scatter(const float* __restrict__ av,
                                                 const float* __restrict__ du,
                                                 const int* __restrict__ rows,
                                                 const int* __restrict__ cols,
                                                 int* __restrict__ row_cursor,
                                                 int2* __restrict__ ep) {
    int i = blockIdx.x * blockDim.x + threadIdx.x;
    if (i < NNZ_C) {
        float m = floorf(0.9f + du[i]);
        if (m != 0.0f) {
            float v = av[i] * m * (float)(1.0 / 0.9);
            int pos = atomicAdd(&row_cursor[rows[i]], 1);
            int2 p;
            p.x = cols[i];
            p.y = __float_as_int(v);
            ep[pos] = p;
        }
    }
}

// ---------------- ego0 = concat(user_emb, item_emb) ----------------
__global__ __launch_bounds__(256) void k_concat(const float* __restrict__ ue,
                                                const float* __restrict__ ie,
                                                float* __restrict__ ego) {
    const int64_t totalU = (int64_t)N_USER_C * EMB_C / 4;
    const int64_t total  = (int64_t)N_NODES_C * EMB_C / 4;
    int64_t stride = (int64_t)gridDim.x * blockDim.x;
    for (int64_t i = (int64_t)blockIdx.x * blockDim.x + threadIdx.x; i < total; i += stride) {
        float4 v = (i < totalU) ? ((const float4*)ue)[i] : ((const float4*)ie)[i - totalU];
        ((float4*)ego)[i] = v;
    }
}

// ---------------- CSR SpMM: one wave per row, 4 edges x 16 dim-quads ----------------
__global__ __launch_bounds__(256) void k_spmm(const int* __restrict__ rs,
                                              const int* __restrict__ cnt,
                                              const int2* __restrict__ ep,
                                              const float* __restrict__ ego,
                                              float* __restrict__ nxt) {
    int wid  = (blockIdx.x * blockDim.x + threadIdx.x) >> 6;   // one wave per row
    int lane = threadIdx.x & 63;
    if (wid >= N_NODES_C) return;
    int start = rs[wid];
    int deg   = cnt[wid];
    int eo = lane >> 4;          // edge slot 0..3
    int l  = lane & 15;          // float4 index within the 64-float row
    const float4* ego4 = (const float4*)ego;
    float4 acc = make_float4(0.f, 0.f, 0.f, 0.f);
    for (int it = eo; it < deg; it += 4) {
        int2 p = ep[start + it];
        float v = __int_as_float(p.y);
        float4 g = ego4[(int64_t)p.x * 16 + l];
        acc.x += v * g.x; acc.y += v * g.y; acc.z += v * g.z; acc.w += v * g.w;
    }
    // reduce the 4 edge slots (lanes xor 16, then xor 32)
    acc.x += __shfl_xor(acc.x, 16); acc.y += __shfl_xor(acc.y, 16);
    acc.z += __shfl_xor(acc.z, 16); acc.w += __shfl_xor(acc.w, 16);
    acc.x += __shfl_xor(acc.x, 32); acc.y += __shfl_xor(acc.y, 32);
    acc.z += __shfl_xor(acc.z, 32); acc.w += __shfl_xor(acc.w, 32);
    if (lane < 16) ((float4*)nxt)[(int64_t)wid * 16 + l] = acc;
}

// ---------------- gather-accumulate the batch rows for hop `hop` ----------------
__global__ __launch_bounds__(256) void k_gather(const float* __restrict__ src,
                                                float* __restrict__ out,
                                                const int* __restrict__ users,
                                                const int* __restrict__ pos,
                                                const int* __restrict__ neg,
                                                const int* __restrict__ ua,
                                                const int* __restrict__ pa,
                                                const int* __restrict__ na,
                                                const int* __restrict__ indexp,
                                                int hop, int init) {
    int t = blockIdx.x * blockDim.x + threadIdx.x;
    if (t >= 3 * BATCH_C * EMB_C) return;
    int d = t & 63;
    int b = t >> 6;            // 0 .. 3*BATCH-1
    int s = b >> 12;           // 0=u, 1=p, 2=n   (BATCH=4096)
    int j = b & (BATCH_C - 1);
    int idx0 = indexp[0];
    int row, a;
    if (s == 0)      { row = users[j] + (idx0 ? N_USER_C : 0); a = ua[j]; }
    else if (s == 1) { row = pos[j]   + (idx0 ? 0 : N_USER_C); a = pa[j]; }
    else             { row = neg[j]   + (idx0 ? 0 : N_USER_C); a = na[j]; }
    if (hop <= a) {
        float x = src[(int64_t)row * EMB_C + d];
        if (init) out[t] = x;
        else      out[t] += x;
    } else if (init) {
        out[t] = 0.0f;
    }
}

// ---------------- divide by (a+1) ----------------
__global__ __launch_bounds__(256) void k_scale(float* __restrict__ out,
                                               const int* __restrict__ ua,
                                               const int* __restrict__ pa,
                                               const int* __restrict__ na) {
    int t = blockIdx.x * blockDim.x + threadIdx.x;
    if (t >= 3 * BATCH_C * EMB_C) return;
    int b = t >> 6;
    int s = b >> 12;
    int j = b & (BATCH_C - 1);
    int a = (s == 0) ? ua[j] : (s == 1) ? pa[j] : na[j];
    out[t] /= (float)(a + 1);
}

extern "C" void kernel_launch(void* const* d_in, const int* in_sizes, int n_in,
                              void* d_out, int out_size, void* d_ws, size_t ws_size,
                              hipStream_t stream) {
    const float* user_emb = (const float*)d_in[0];
    const float* item_emb = (const float*)d_in[1];
    const float* adj_vals = (const float*)d_in[2];
    const float* drop_u   = (const float*)d_in[3];
    const int*   adj_rows = (const int*)d_in[4];
    const int*   adj_cols = (const int*)d_in[5];
    const int*   users    = (const int*)d_in[6];
    const int*   pos_it   = (const int*)d_in[7];
    const int*   neg_it   = (const int*)d_in[8];
    const int*   u_a      = (const int*)d_in[9];
    const int*   p_a      = (const int*)d_in[10];
    const int*   n_a      = (const int*)d_in[11];
    const int*   indexp   = (const int*)d_in[12];
    float* out = (float*)d_out;

    // workspace layout
    const size_t egoElems = (size_t)N_NODES_C * EMB_C;       // 9.6M floats
    float* bufA       = (float*)d_ws;                        // 38.4 MB
    float* bufB       = bufA + egoElems;                     // 38.4 MB
    int2*  ep         = (int2*)(bufB + egoElems);            // 9.6 MB
    int*   cnt        = (int*)(ep + NNZ_C);                  // 600 KB
    int*   row_start  = cnt + N_NODES_C;                     // 600 KB
    int*   row_cursor = row_start + N_NODES_C + 1;           // 600 KB

    // ---- one-time CSR build (amortized over 4 SpMM layers) ----
    hipMemsetAsync(cnt, 0, N_NODES_C * sizeof(int), stream);
    k_hist<<<(NNZ_C + 255) / 256, 256, 0, stream>>>(drop_u, adj_rows, cnt);
    k_scan<<<1, SCAN_T, 0, stream>>>(cnt, row_start, row_cursor);
    k_scatter<<<(NNZ_C + 255) / 256, 256, 0, stream>>>(adj_vals, drop_u, adj_rows,
                                                       adj_cols, row_cursor, ep);

    // ---- ego0 and hop-0 gather ----
    k_concat<<<2048, 256, 0, stream>>>(user_emb, item_emb, bufA);
    const int GT = 3 * BATCH_C * EMB_C;
    k_gather<<<(GT + 255) / 256, 256, 0, stream>>>(bufA, out, users, pos_it, neg_it,
                                                   u_a, p_a, n_a, indexp, 0, 1);

    // ---- 4 atomic-free SpMM hops with incremental gather ----
    float* cur = bufA;
    float* nxt = bufB;
    const int SPMM_BLOCKS = (N_NODES_C * 64 + 255) / 256;    // one wave per row
    for (int hop = 1; hop <= 4; ++hop) {
        k_spmm<<<SPMM_BLOCKS, 256, 0, stream>>>(row_start, cnt, ep, cur, nxt);
        k_gather<<<(GT + 255) / 256, 256, 0, stream>>>(nxt, out, users, pos_it, neg_it,
                                                       u_a, p_a, n_a, indexp, hop, 0);
        float* tmp = cur; cur = nxt; nxt = tmp;
    }
    // ---- final divide by (a+1) ----
    k_scale<<<(GT + 255) / 256, 256, 0, stream>>>(out, u_a, p_a, n_a);
}

// Round 3
// 403.703 us; speedup vs baseline: 2.6114x; 1.9344x over previous
//
#include <hip/hip_runtime.h>
#include <stdint.h>

#define N_USER_C  50000
#define N_ITEM_C  100000
#define N_NODES_C 150000
#define EMB_C     64
#define NNZ_C     1200000
#define BATCH_C   4096
#define SCAN_CHUNK 2048
#define SCAN_BLOCKS ((N_NODES_C + SCAN_CHUNK - 1) / SCAN_CHUNK)   // 74

// ---------------- histogram of kept-edge rows ----------------
__global__ __launch_bounds__(256) void k_hist(const float* __restrict__ du,
                                              const int* __restrict__ rows,
                                              int* __restrict__ cnt) {
    int i = blockIdx.x * blockDim.x + threadIdx.x;
    if (i < NNZ_C) {
        float m = floorf(0.9f + du[i]);      // 0/1 keep mask, matches jnp.floor
        if (m != 0.0f) atomicAdd(&cnt[rows[i]], 1);
    }
}

// ---------------- device-wide exclusive scan, 3 phases ----------------
__global__ __launch_bounds__(256) void k_scan_a(const int* __restrict__ cnt,
                                                int* __restrict__ bsum) {
    __shared__ int red[256];
    int base = blockIdx.x * SCAN_CHUNK;
    int s = 0;
    for (int i = threadIdx.x; i < SCAN_CHUNK; i += 256) {
        int idx = base + i;
        if (idx < N_NODES_C) s += cnt[idx];
    }
    red[threadIdx.x] = s;
    __syncthreads();
    for (int off = 128; off > 0; off >>= 1) {
        if (threadIdx.x < off) red[threadIdx.x] += red[threadIdx.x + off];
        __syncthreads();
    }
    if (threadIdx.x == 0) bsum[blockIdx.x] = red[0];
}

__global__ __launch_bounds__(128) void k_scan_b(const int* __restrict__ bsum,
                                                int* __restrict__ bpre) {
    __shared__ int sh[128];
    int tid = threadIdx.x;
    int v0 = (tid < SCAN_BLOCKS) ? bsum[tid] : 0;
    sh[tid] = v0;
    __syncthreads();
    for (int off = 1; off < 128; off <<= 1) {
        int v = (tid >= off) ? sh[tid - off] : 0;
        __syncthreads();
        sh[tid] += v;
        __syncthreads();
    }
    if (tid < SCAN_BLOCKS) bpre[tid] = sh[tid] - v0;   // exclusive prefix
}

__global__ __launch_bounds__(256) void k_scan_c(const int* __restrict__ cnt,
                                                const int* __restrict__ bpre,
                                                int* __restrict__ row_start,
                                                int* __restrict__ row_cursor) {
    __shared__ int sh[SCAN_CHUNK];
    __shared__ int tsum[256];
    int base = blockIdx.x * SCAN_CHUNK;
    for (int i = threadIdx.x; i < SCAN_CHUNK; i += 256) {
        int idx = base + i;
        sh[i] = (idx < N_NODES_C) ? cnt[idx] : 0;
    }
    __syncthreads();
    int t = threadIdx.x;
    int local[8];
    int run = 0;
    #pragma unroll
    for (int i = 0; i < 8; ++i) { local[i] = run; run += sh[t * 8 + i]; }
    tsum[t] = run;
    __syncthreads();
    for (int off = 1; off < 256; off <<= 1) {
        int v = (t >= off) ? tsum[t - off] : 0;
        __syncthreads();
        tsum[t] += v;
        __syncthreads();
    }
    int texcl = tsum[t] - run;
    int boff = bpre[blockIdx.x];
    #pragma unroll
    for (int i = 0; i < 8; ++i) {
        int idx = base + t * 8 + i;
        if (idx < N_NODES_C) {
            int v = boff + texcl + local[i];
            row_start[idx]  = v;
            row_cursor[idx] = v;
        }
    }
}

// ---------------- scatter kept edges into row-sorted (col,val) payload ----------------
__global__ __launch_bounds__(256) void k_scatter(const float* __restrict__ av,
                                                 const float* __restrict__ du,
                                                 const int* __restrict__ rows,
                                                 const int* __restrict__ cols,
                                                 int* __restrict__ row_cursor,
                                                 int2* __restrict__ ep) {
    int i = blockIdx.x * blockDim.x + threadIdx.x;
    if (i < NNZ_C) {
        float m = floorf(0.9f + du[i]);
        if (m != 0.0f) {
            float v = av[i] * m * (float)(1.0 / 0.9);
            int pos = atomicAdd(&row_cursor[rows[i]], 1);
            int2 p;
            p.x = cols[i];
            p.y = __float_as_int(v);
            ep[pos] = p;
        }
    }
}

// ---------------- ego0 = concat(user_emb, item_emb) ----------------
__global__ __launch_bounds__(256) void k_concat(const float* __restrict__ ue,
                                                const float* __restrict__ ie,
                                                float* __restrict__ ego) {
    const int64_t totalU = (int64_t)N_USER_C * EMB_C / 4;
    const int64_t total  = (int64_t)N_NODES_C * EMB_C / 4;
    int64_t stride = (int64_t)gridDim.x * blockDim.x;
    for (int64_t i = (int64_t)blockIdx.x * blockDim.x + threadIdx.x; i < total; i += stride) {
        float4 v = (i < totalU) ? ((const float4*)ue)[i] : ((const float4*)ie)[i - totalU];
        ((float4*)ego)[i] = v;
    }
}

// ---------------- CSR SpMM: one wave per row, 4 edges x 16 dim-quads ----------------
__global__ __launch_bounds__(256) void k_spmm(const int* __restrict__ rs,
                                              const int* __restrict__ cnt,
                                              const int2* __restrict__ ep,
                                              const float* __restrict__ ego,
                                              float* __restrict__ nxt) {
    int wid  = (blockIdx.x * blockDim.x + threadIdx.x) >> 6;   // one wave per row
    int lane = threadIdx.x & 63;
    if (wid >= N_NODES_C) return;
    int start = rs[wid];
    int deg   = cnt[wid];
    int eo = lane >> 4;          // edge slot 0..3
    int l  = lane & 15;          // float4 index within the 64-float row
    const float4* ego4 = (const float4*)ego;
    float4 acc = make_float4(0.f, 0.f, 0.f, 0.f);
    for (int it = eo; it < deg; it += 4) {
        int2 p = ep[start + it];
        float v = __int_as_float(p.y);
        float4 g = ego4[(int64_t)p.x * 16 + l];
        acc.x += v * g.x; acc.y += v * g.y; acc.z += v * g.z; acc.w += v * g.w;
    }
    acc.x += __shfl_xor(acc.x, 16); acc.y += __shfl_xor(acc.y, 16);
    acc.z += __shfl_xor(acc.z, 16); acc.w += __shfl_xor(acc.w, 16);
    acc.x += __shfl_xor(acc.x, 32); acc.y += __shfl_xor(acc.y, 32);
    acc.z += __shfl_xor(acc.z, 32); acc.w += __shfl_xor(acc.w, 32);
    if (lane < 16) ((float4*)nxt)[(int64_t)wid * 16 + l] = acc;
}

// ---------------- gather-accumulate the batch rows for hop `hop` ----------------
__global__ __launch_bounds__(256) void k_gather(const float* __restrict__ src,
                                                float* __restrict__ out,
                                                const int* __restrict__ users,
                                                const int* __restrict__ pos,
                                                const int* __restrict__ neg,
                                                const int* __restrict__ ua,
                                                const int* __restrict__ pa,
                                                const int* __restrict__ na,
                                                const int* __restrict__ indexp,
                                                int hop, int init) {
    int t = blockIdx.x * blockDim.x + threadIdx.x;
    if (t >= 3 * BATCH_C * EMB_C) return;
    int d = t & 63;
    int b = t >> 6;            // 0 .. 3*BATCH-1
    int s = b >> 12;           // 0=u, 1=p, 2=n   (BATCH=4096)
    int j = b & (BATCH_C - 1);
    int idx0 = indexp[0];
    int row, a;
    if (s == 0)      { row = users[j] + (idx0 ? N_USER_C : 0); a = ua[j]; }
    else if (s == 1) { row = pos[j]   + (idx0 ? 0 : N_USER_C); a = pa[j]; }
    else             { row = neg[j]   + (idx0 ? 0 : N_USER_C); a = na[j]; }
    if (hop <= a) {
        float x = src[(int64_t)row * EMB_C + d];
        if (init) out[t] = x;
        else      out[t] += x;
    } else if (init) {
        out[t] = 0.0f;
    }
}

// ---------------- divide by (a+1) ----------------
__global__ __launch_bounds__(256) void k_scale(float* __restrict__ out,
                                               const int* __restrict__ ua,
                                               const int* __restrict__ pa,
                                               const int* __restrict__ na) {
    int t = blockIdx.x * blockDim.x + threadIdx.x;
    if (t >= 3 * BATCH_C * EMB_C) return;
    int b = t >> 6;
    int s = b >> 12;
    int j = b & (BATCH_C - 1);
    int a = (s == 0) ? ua[j] : (s == 1) ? pa[j] : na[j];
    out[t] /= (float)(a + 1);
}

extern "C" void kernel_launch(void* const* d_in, const int* in_sizes, int n_in,
                              void* d_out, int out_size, void* d_ws, size_t ws_size,
                              hipStream_t stream) {
    const float* user_emb = (const float*)d_in[0];
    const float* item_emb = (const float*)d_in[1];
    const float* adj_vals = (const float*)d_in[2];
    const float* drop_u   = (const float*)d_in[3];
    const int*   adj_rows = (const int*)d_in[4];
    const int*   adj_cols = (const int*)d_in[5];
    const int*   users    = (const int*)d_in[6];
    const int*   pos_it   = (const int*)d_in[7];
    const int*   neg_it   = (const int*)d_in[8];
    const int*   u_a      = (const int*)d_in[9];
    const int*   p_a      = (const int*)d_in[10];
    const int*   n_a      = (const int*)d_in[11];
    const int*   indexp   = (const int*)d_in[12];
    float* out = (float*)d_out;

    // workspace layout
    const size_t egoElems = (size_t)N_NODES_C * EMB_C;       // 9.6M floats
    float* bufA       = (float*)d_ws;                        // 38.4 MB
    float* bufB       = bufA + egoElems;                     // 38.4 MB
    int2*  ep         = (int2*)(bufB + egoElems);            // 9.6 MB
    int*   cnt        = (int*)(ep + NNZ_C);                  // 600 KB
    int*   row_start  = cnt + N_NODES_C;                     // 600 KB
    int*   row_cursor = row_start + N_NODES_C + 1;           // 600 KB
    int*   bsum       = row_cursor + N_NODES_C + 1;          // 74
    int*   bpre       = bsum + 256;                          // 74

    // ---- one-time CSR build (amortized over 4 SpMM layers) ----
    hipMemsetAsync(cnt, 0, N_NODES_C * sizeof(int), stream);
    k_hist<<<(NNZ_C + 255) / 256, 256, 0, stream>>>(drop_u, adj_rows, cnt);
    k_scan_a<<<SCAN_BLOCKS, 256, 0, stream>>>(cnt, bsum);
    k_scan_b<<<1, 128, 0, stream>>>(bsum, bpre);
    k_scan_c<<<SCAN_BLOCKS, 256, 0, stream>>>(cnt, bpre, row_start, row_cursor);
    k_scatter<<<(NNZ_C + 255) / 256, 256, 0, stream>>>(adj_vals, drop_u, adj_rows,
                                                       adj_cols, row_cursor, ep);

    // ---- ego0 and hop-0 gather ----
    k_concat<<<2048, 256, 0, stream>>>(user_emb, item_emb, bufA);
    const int GT = 3 * BATCH_C * EMB_C;
    k_gather<<<(GT + 255) / 256, 256, 0, stream>>>(bufA, out, users, pos_it, neg_it,
                                                   u_a, p_a, n_a, indexp, 0, 1);

    // ---- 4 atomic-free SpMM hops with incremental gather ----
    float* cur = bufA;
    float* nxt = bufB;
    const int SPMM_BLOCKS = (N_NODES_C * 64 + 255) / 256;    // one wave per row
    for (int hop = 1; hop <= 4; ++hop) {
        k_spmm<<<SPMM_BLOCKS, 256, 0, stream>>>(row_start, cnt, ep, cur, nxt);
        k_gather<<<(GT + 255) / 256, 256, 0, stream>>>(nxt, out, users, pos_it, neg_it,
                                                       u_a, p_a, n_a, indexp, hop, 0);
        float* tmp = cur; cur = nxt; nxt = tmp;
    }
    // ---- final divide by (a+1) ----
    k_scale<<<(GT + 255) / 256, 256, 0, stream>>>(out, u_a, p_a, n_a);
}

// Round 4
// 342.916 us; speedup vs baseline: 3.0743x; 1.1773x over previous
//
#include <hip/hip_runtime.h>
#include <stdint.h>

#define N_USER_C  50000
#define N_ITEM_C  100000
#define N_NODES_C 150000
#define EMB_C     64
#define NNZ_C     1200000
#define BATCH_C   4096

#define BKT_SHIFT 9                                   // 512 rows per bucket
#define BKT_ROWS  (1 << BKT_SHIFT)
#define NB        ((N_NODES_C + BKT_ROWS - 1) / BKT_ROWS)   // 293
#define CH        8192                                // edges per binning block
#define NBLK      ((NNZ_C + CH - 1) / CH)             // 147
#define N2        (NB * NBLK)                         // 43071

// ---------------- pass A: per-(block,bucket) histogram of kept edges ----------------
__global__ __launch_bounds__(1024) void k_bin_count(const float* __restrict__ du,
                                                    const int* __restrict__ rows,
                                                    int* __restrict__ cnt2) {
    __shared__ int bk[NB];
    int t = threadIdx.x, blk = blockIdx.x;
    for (int i = t; i < NB; i += 1024) bk[i] = 0;
    __syncthreads();
    int base = blk * CH;
    for (int i = 0; i < CH; i += 1024) {
        int e = base + i + t;
        if (e < NNZ_C && floorf(0.9f + du[e]) != 0.0f)
            atomicAdd(&bk[rows[e] >> BKT_SHIFT], 1);
    }
    __syncthreads();
    for (int i = t; i < NB; i += 1024) cnt2[i * NBLK + blk] = bk[i];
}

// ---------------- pass B: one-block exclusive scan of cnt2 ----------------
__global__ __launch_bounds__(1024) void k_scan2(const int* __restrict__ cnt2,
                                                int* __restrict__ base2,
                                                int* __restrict__ row_start) {
    __shared__ int tsum[1024];
    int t = threadIdx.x;
    const int CHK = (N2 + 1023) / 1024;               // 43
    int lo = t * CHK;
    int hi = lo + CHK; if (hi > N2) hi = N2;
    int s = 0;
    for (int i = lo; i < hi; ++i) s += cnt2[i];
    tsum[t] = s;
    __syncthreads();
    for (int off = 1; off < 1024; off <<= 1) {
        int v = (t >= off) ? tsum[t - off] : 0;
        __syncthreads();
        tsum[t] += v;
        __syncthreads();
    }
    int run = tsum[t] - s;
    for (int i = lo; i < hi; ++i) { base2[i] = run; run += cnt2[i]; }
    if (t == 1023) {
        base2[N2] = tsum[1023];                       // total kept edges
        row_start[N_NODES_C] = tsum[1023];            // CSR sentinel
    }
}

// ---------------- pass C: bucket-sorted write of (col,val) + row ----------------
__global__ __launch_bounds__(1024) void k_bin_write(const float* __restrict__ av,
                                                    const float* __restrict__ du,
                                                    const int* __restrict__ rows,
                                                    const int* __restrict__ cols,
                                                    const int* __restrict__ base2,
                                                    int2* __restrict__ ev,
                                                    int* __restrict__ er) {
    __shared__ int cur[NB];
    int t = threadIdx.x, blk = blockIdx.x;
    for (int i = t; i < NB; i += 1024) cur[i] = base2[i * NBLK + blk];
    __syncthreads();
    int base = blk * CH;
    for (int i = 0; i < CH; i += 1024) {
        int e = base + i + t;
        if (e < NNZ_C) {
            float m = floorf(0.9f + du[e]);
            if (m != 0.0f) {
                float v = av[e] * m * (float)(1.0 / 0.9);
                int r = rows[e];
                int pos = atomicAdd(&cur[r >> BKT_SHIFT], 1);
                int2 p; p.x = cols[e]; p.y = __float_as_int(v);
                ev[pos] = p;
                er[pos] = r;
            }
        }
    }
}

// ---------------- pass D: per-bucket exact row sort (LDS hist+scan+scatter) ----------------
__global__ __launch_bounds__(256) void k_bucket_sort(const int2* __restrict__ ev,
                                                     const int* __restrict__ er,
                                                     const int* __restrict__ base2,
                                                     int2* __restrict__ ep,
                                                     int* __restrict__ row_start) {
    __shared__ int rowcnt[BKT_ROWS];
    __shared__ int cursor[BKT_ROWS];
    __shared__ int tsum[256];
    int t = threadIdx.x, k = blockIdx.x;
    int rowBase = k << BKT_SHIFT;
    int bstart = base2[k * NBLK];
    int bend   = base2[(k + 1) * NBLK];               // k=NB-1 hits base2[N2]=total
    for (int i = t; i < BKT_ROWS; i += 256) rowcnt[i] = 0;
    __syncthreads();
    for (int e = bstart + t; e < bend; e += 256)
        atomicAdd(&rowcnt[er[e] - rowBase], 1);
    __syncthreads();
    int a = rowcnt[2 * t], b = rowcnt[2 * t + 1];
    tsum[t] = a + b;
    __syncthreads();
    for (int off = 1; off < 256; off <<= 1) {
        int v = (t >= off) ? tsum[t - off] : 0;
        __syncthreads();
        tsum[t] += v;
        __syncthreads();
    }
    int excl = tsum[t] - (a + b);
    cursor[2 * t]     = excl;
    cursor[2 * t + 1] = excl + a;
    int gr = rowBase + 2 * t;
    if (gr < N_NODES_C)     row_start[gr]     = bstart + excl;
    if (gr + 1 < N_NODES_C) row_start[gr + 1] = bstart + excl + a;
    __syncthreads();
    for (int e = bstart + t; e < bend; e += 256) {
        int r = er[e];
        int slot = atomicAdd(&cursor[r - rowBase], 1);
        ep[bstart + slot] = ev[e];
    }
}

// ---------------- CSR SpMM: one wave per row, 4 edges x 16 dim-quads ----------------
__global__ __launch_bounds__(256) void k_spmm(const int* __restrict__ rs,
                                              const int2* __restrict__ ep,
                                              const float4* __restrict__ egoU,
                                              const float4* __restrict__ egoI,
                                              int pivot,
                                              float* __restrict__ nxt) {
    int wid  = (blockIdx.x * blockDim.x + threadIdx.x) >> 6;   // one wave per row
    int lane = threadIdx.x & 63;
    if (wid >= N_NODES_C) return;
    int start = rs[wid];
    int end   = rs[wid + 1];
    int eo = lane >> 4;          // edge slot 0..3
    int l  = lane & 15;          // float4 index within the 64-float row
    float4 acc = make_float4(0.f, 0.f, 0.f, 0.f);
    #pragma unroll 2
    for (int it = start + eo; it < end; it += 4) {
        int2 p = ep[it];
        float v = __int_as_float(p.y);
        const float4* s = (p.x < pivot) ? (egoU + (int64_t)p.x * 16)
                                        : (egoI + (int64_t)(p.x - pivot) * 16);
        float4 g = s[l];
        acc.x += v * g.x; acc.y += v * g.y; acc.z += v * g.z; acc.w += v * g.w;
    }
    acc.x += __shfl_xor(acc.x, 16); acc.y += __shfl_xor(acc.y, 16);
    acc.z += __shfl_xor(acc.z, 16); acc.w += __shfl_xor(acc.w, 16);
    acc.x += __shfl_xor(acc.x, 32); acc.y += __shfl_xor(acc.y, 32);
    acc.z += __shfl_xor(acc.z, 32); acc.w += __shfl_xor(acc.w, 32);
    if (lane < 16) ((float4*)nxt)[(int64_t)wid * 16 + l] = acc;
}

// ---------------- gather-accumulate the batch rows for hop `hop` ----------------
__global__ __launch_bounds__(256) void k_gather(const float* __restrict__ srcU,
                                                const float* __restrict__ srcI,
                                                int pivot,
                                                float* __restrict__ out,
                                                const int* __restrict__ users,
                                                const int* __restrict__ pos,
                                                const int* __restrict__ neg,
                                                const int* __restrict__ ua,
                                                const int* __restrict__ pa,
                                                const int* __restrict__ na,
                                                const int* __restrict__ indexp,
                                                int hop, int init) {
    int t = blockIdx.x * blockDim.x + threadIdx.x;
    if (t >= 3 * BATCH_C * EMB_C) return;
    int d = t & 63;
    int b = t >> 6;            // 0 .. 3*BATCH-1
    int s = b >> 12;           // 0=u, 1=p, 2=n   (BATCH=4096)
    int j = b & (BATCH_C - 1);
    int idx0 = indexp[0];
    int row, a;
    if (s == 0)      { row = users[j] + (idx0 ? N_USER_C : 0); a = ua[j]; }
    else if (s == 1) { row = pos[j]   + (idx0 ? 0 : N_USER_C); a = pa[j]; }
    else             { row = neg[j]   + (idx0 ? 0 : N_USER_C); a = na[j]; }
    if (hop <= a) {
        const float* sp = (row < pivot) ? (srcU + (int64_t)row * EMB_C)
                                        : (srcI + (int64_t)(row - pivot) * EMB_C);
        float x = sp[d];
        if (init) out[t] = x;
        else      out[t] += x;
    } else if (init) {
        out[t] = 0.0f;
    }
}

// ---------------- divide by (a+1) ----------------
__global__ __launch_bounds__(256) void k_scale(float* __restrict__ out,
                                               const int* __restrict__ ua,
                                               const int* __restrict__ pa,
                                               const int* __restrict__ na) {
    int t = blockIdx.x * blockDim.x + threadIdx.x;
    if (t >= 3 * BATCH_C * EMB_C) return;
    int b = t >> 6;
    int s = b >> 12;
    int j = b & (BATCH_C - 1);
    int a = (s == 0) ? ua[j] : (s == 1) ? pa[j] : na[j];
    out[t] /= (float)(a + 1);
}

extern "C" void kernel_launch(void* const* d_in, const int* in_sizes, int n_in,
                              void* d_out, int out_size, void* d_ws, size_t ws_size,
                              hipStream_t stream) {
    const float* user_emb = (const float*)d_in[0];
    const float* item_emb = (const float*)d_in[1];
    const float* adj_vals = (const float*)d_in[2];
    const float* drop_u   = (const float*)d_in[3];
    const int*   adj_rows = (const int*)d_in[4];
    const int*   adj_cols = (const int*)d_in[5];
    const int*   users    = (const int*)d_in[6];
    const int*   pos_it   = (const int*)d_in[7];
    const int*   neg_it   = (const int*)d_in[8];
    const int*   u_a      = (const int*)d_in[9];
    const int*   p_a      = (const int*)d_in[10];
    const int*   n_a      = (const int*)d_in[11];
    const int*   indexp   = (const int*)d_in[12];
    float* out = (float*)d_out;

    // workspace layout
    const size_t egoElems = (size_t)N_NODES_C * EMB_C;       // 9.6M floats
    float* bufA      = (float*)d_ws;                         // 38.4 MB
    float* bufB      = bufA + egoElems;                      // 38.4 MB
    int2*  ep        = (int2*)(bufB + egoElems);             // 9.6 MB (final CSR payload)
    int*   row_start = (int*)(ep + NNZ_C);                   // 600 KB (+sentinel)
    int*   cnt2      = row_start + N_NODES_C + 1;            // ~172 KB
    int*   base2     = cnt2 + N2 + 1;                        // ~172 KB
    // build temporaries aliased into bufB (free until hop-2 output)
    int2*  ev        = (int2*)bufB;                          // 9.6 MB
    int*   er        = (int*)(ev + NNZ_C);                   // 4.8 MB

    // ---- CSR build: bucketed counting sort, all randomness L2-confined ----
    k_bin_count<<<NBLK, 1024, 0, stream>>>(drop_u, adj_rows, cnt2);
    k_scan2<<<1, 1024, 0, stream>>>(cnt2, base2, row_start);
    k_bin_write<<<NBLK, 1024, 0, stream>>>(adj_vals, drop_u, adj_rows, adj_cols,
                                           base2, ev, er);
    k_bucket_sort<<<NB, 256, 0, stream>>>(ev, er, base2, ep, row_start);

    // ---- hop-0 gather straight from the embedding tables ----
    const int GT = 3 * BATCH_C * EMB_C;
    k_gather<<<(GT + 255) / 256, 256, 0, stream>>>(user_emb, item_emb, N_USER_C, out,
                                                   users, pos_it, neg_it,
                                                   u_a, p_a, n_a, indexp, 0, 1);

    // ---- 4 atomic-free SpMM hops with incremental gather ----
    const int SPMM_BLOCKS = (N_NODES_C * 64 + 255) / 256;    // one wave per row
    // hop 1: read directly from (user_emb, item_emb)
    k_spmm<<<SPMM_BLOCKS, 256, 0, stream>>>(row_start, ep,
                                            (const float4*)user_emb,
                                            (const float4*)item_emb, N_USER_C, bufA);
    k_gather<<<(GT + 255) / 256, 256, 0, stream>>>(bufA, bufA, N_NODES_C, out,
                                                   users, pos_it, neg_it,
                                                   u_a, p_a, n_a, indexp, 1, 0);
    float* cur = bufA;
    float* nxt = bufB;
    for (int hop = 2; hop <= 4; ++hop) {
        k_spmm<<<SPMM_BLOCKS, 256, 0, stream>>>(row_start, ep,
                                                (const float4*)cur, (const float4*)cur,
                                                N_NODES_C, nxt);
        k_gather<<<(GT + 255) / 256, 256, 0, stream>>>(nxt, nxt, N_NODES_C, out,
                                                       users, pos_it, neg_it,
                                                       u_a, p_a, n_a, indexp, hop, 0);
        float* tmp = cur; cur = nxt; nxt = tmp;
    }
    // ---- final divide by (a+1) ----
    k_scale<<<(GT + 255) / 256, 256, 0, stream>>>(out, u_a, p_a, n_a);
}

// Round 5
// 235.928 us; speedup vs baseline: 4.4684x; 1.4535x over previous
//
#include <hip/hip_runtime.h>
#include <stdint.h>

#define N_USER_C  50000
#define N_ITEM_C  100000
#define N_NODES_C 150000
#define EMB_C     64
#define NNZ_C     1200000
#define BATCH_C   4096

#define BKT_SHIFT 9                                   // 512 rows per bucket
#define BKT_ROWS  (1 << BKT_SHIFT)
#define NB        ((N_NODES_C + BKT_ROWS - 1) / BKT_ROWS)   // 293
#define CH        8192                                // edges per binning block
#define NBLK      ((NNZ_C + CH - 1) / CH)             // 147
#define N2        (NB * NBLK)                         // 43071

// ---------------- pass A: per-(block,bucket) histogram of kept edges ----------------
__global__ __launch_bounds__(1024) void k_bin_count(const float* __restrict__ du,
                                                    const int* __restrict__ rows,
                                                    int* __restrict__ cnt2) {
    __shared__ int bk[NB];
    int t = threadIdx.x, blk = blockIdx.x;
    for (int i = t; i < NB; i += 1024) bk[i] = 0;
    __syncthreads();
    int base = blk * CH;
    for (int i = 0; i < CH; i += 1024) {
        int e = base + i + t;
        if (e < NNZ_C && floorf(0.9f + du[e]) != 0.0f)
            atomicAdd(&bk[rows[e] >> BKT_SHIFT], 1);
    }
    __syncthreads();
    for (int i = t; i < NB; i += 1024) cnt2[i * NBLK + blk] = bk[i];
}

// ---------------- pass B1: per-bucket totals ----------------
__global__ __launch_bounds__(256) void k_btot(const int* __restrict__ cnt2,
                                              int* __restrict__ btot) {
    __shared__ int red[256];
    int t = threadIdx.x, i = blockIdx.x;
    red[t] = (t < NBLK) ? cnt2[i * NBLK + t] : 0;
    __syncthreads();
    for (int off = 128; off > 0; off >>= 1) {
        if (t < off) red[t] += red[t + off];
        __syncthreads();
    }
    if (t == 0) btot[i] = red[0];
}

// ---------------- pass B2: scan of 293 bucket totals ----------------
__global__ __launch_bounds__(512) void k_bbase(const int* __restrict__ btot,
                                               int* __restrict__ bbase,
                                               int* __restrict__ base2,
                                               int* __restrict__ row_start) {
    __shared__ int sh[512];
    int t = threadIdx.x;
    int v0 = (t < NB) ? btot[t] : 0;
    sh[t] = v0;
    __syncthreads();
    for (int off = 1; off < 512; off <<= 1) {
        int v = (t >= off) ? sh[t - off] : 0;
        __syncthreads();
        sh[t] += v;
        __syncthreads();
    }
    if (t < NB) bbase[t] = sh[t] - v0;                 // exclusive bucket prefix
    if (t == 511) {
        base2[N2] = sh[511];                           // total kept edges
        row_start[N_NODES_C] = sh[511];                // CSR sentinel
    }
}

// ---------------- pass B3: per-bucket scan of 147 block counts ----------------
__global__ __launch_bounds__(256) void k_bscan(const int* __restrict__ cnt2,
                                               const int* __restrict__ bbase,
                                               int* __restrict__ base2) {
    __shared__ int sh[256];
    int t = threadIdx.x, i = blockIdx.x;
    int v0 = (t < NBLK) ? cnt2[i * NBLK + t] : 0;
    sh[t] = v0;
    __syncthreads();
    for (int off = 1; off < 256; off <<= 1) {
        int v = (t >= off) ? sh[t - off] : 0;
        __syncthreads();
        sh[t] += v;
        __syncthreads();
    }
    if (t < NBLK) base2[i * NBLK + t] = bbase[i] + sh[t] - v0;
}

// ---------------- pass C: bucket-sorted write of (col,val) + row ----------------
__global__ __launch_bounds__(1024) void k_bin_write(const float* __restrict__ av,
                                                    const float* __restrict__ du,
                                                    const int* __restrict__ rows,
                                                    const int* __restrict__ cols,
                                                    const int* __restrict__ base2,
                                                    int2* __restrict__ ev,
                                                    int* __restrict__ er) {
    __shared__ int cur[NB];
    int t = threadIdx.x, blk = blockIdx.x;
    for (int i = t; i < NB; i += 1024) cur[i] = base2[i * NBLK + blk];
    __syncthreads();
    int base = blk * CH;
    for (int i = 0; i < CH; i += 1024) {
        int e = base + i + t;
        if (e < NNZ_C) {
            float m = floorf(0.9f + du[e]);
            if (m != 0.0f) {
                float v = av[e] * m * (float)(1.0 / 0.9);
                int r = rows[e];
                int pos = atomicAdd(&cur[r >> BKT_SHIFT], 1);
                int2 p; p.x = cols[e]; p.y = __float_as_int(v);
                ev[pos] = p;
                er[pos] = r;
            }
        }
    }
}

// ---------------- pass D: per-bucket exact row sort (LDS hist+scan+scatter) ----------------
__global__ __launch_bounds__(256) void k_bucket_sort(const int2* __restrict__ ev,
                                                     const int* __restrict__ er,
                                                     const int* __restrict__ base2,
                                                     int2* __restrict__ ep,
                                                     int* __restrict__ row_start) {
    __shared__ int rowcnt[BKT_ROWS];
    __shared__ int cursor[BKT_ROWS];
    __shared__ int tsum[256];
    int t = threadIdx.x, k = blockIdx.x;
    int rowBase = k << BKT_SHIFT;
    int bstart = base2[k * NBLK];
    int bend   = base2[(k + 1) * NBLK];               // k=NB-1 hits base2[N2]=total
    for (int i = t; i < BKT_ROWS; i += 256) rowcnt[i] = 0;
    __syncthreads();
    for (int e = bstart + t; e < bend; e += 256)
        atomicAdd(&rowcnt[er[e] - rowBase], 1);
    __syncthreads();
    int a = rowcnt[2 * t], b = rowcnt[2 * t + 1];
    tsum[t] = a + b;
    __syncthreads();
    for (int off = 1; off < 256; off <<= 1) {
        int v = (t >= off) ? tsum[t - off] : 0;
        __syncthreads();
        tsum[t] += v;
        __syncthreads();
    }
    int excl = tsum[t] - (a + b);
    cursor[2 * t]     = excl;
    cursor[2 * t + 1] = excl + a;
    int gr = rowBase + 2 * t;
    if (gr < N_NODES_C)     row_start[gr]     = bstart + excl;
    if (gr + 1 < N_NODES_C) row_start[gr + 1] = bstart + excl + a;
    __syncthreads();
    for (int e = bstart + t; e < bend; e += 256) {
        int r = er[e];
        int slot = atomicAdd(&cursor[r - rowBase], 1);
        ep[bstart + slot] = ev[e];
    }
}

// ---------------- CSR SpMM: one wave per row, 4 edges x 16 dim-quads ----------------
__global__ __launch_bounds__(256) void k_spmm(const int* __restrict__ rs,
                                              const int2* __restrict__ ep,
                                              const float4* __restrict__ egoU,
                                              const float4* __restrict__ egoI,
                                              int pivot,
                                              float* __restrict__ nxt) {
    int wid  = (blockIdx.x * blockDim.x + threadIdx.x) >> 6;   // one wave per row
    int lane = threadIdx.x & 63;
    if (wid >= N_NODES_C) return;
    int start = rs[wid];
    int end   = rs[wid + 1];
    int eo = lane >> 4;          // edge slot 0..3
    int l  = lane & 15;          // float4 index within the 64-float row
    float4 acc = make_float4(0.f, 0.f, 0.f, 0.f);
    #pragma unroll 2
    for (int it = start + eo; it < end; it += 4) {
        int2 p = ep[it];
        float v = __int_as_float(p.y);
        const float4* s = (p.x < pivot) ? (egoU + (int64_t)p.x * 16)
                                        : (egoI + (int64_t)(p.x - pivot) * 16);
        float4 g = s[l];
        acc.x += v * g.x; acc.y += v * g.y; acc.z += v * g.z; acc.w += v * g.w;
    }
    acc.x += __shfl_xor(acc.x, 16); acc.y += __shfl_xor(acc.y, 16);
    acc.z += __shfl_xor(acc.z, 16); acc.w += __shfl_xor(acc.w, 16);
    acc.x += __shfl_xor(acc.x, 32); acc.y += __shfl_xor(acc.y, 32);
    acc.z += __shfl_xor(acc.z, 32); acc.w += __shfl_xor(acc.w, 32);
    if (lane < 16) ((float4*)nxt)[(int64_t)wid * 16 + l] = acc;
}

// ---------------- fused hop-4: per batch entry with a==4, one wave CSR dot -> out ----------------
__global__ __launch_bounds__(256) void k_spmm_g4(const int* __restrict__ rs,
                                                 const int2* __restrict__ ep,
                                                 const float4* __restrict__ ego,
                                                 float* __restrict__ out,
                                                 const int* __restrict__ users,
                                                 const int* __restrict__ pos,
                                                 const int* __restrict__ neg,
                                                 const int* __restrict__ ua,
                                                 const int* __restrict__ pa,
                                                 const int* __restrict__ na,
                                                 const int* __restrict__ indexp) {
    int wid  = (blockIdx.x * blockDim.x + threadIdx.x) >> 6;   // batch slot 0..3*BATCH-1
    int lane = threadIdx.x & 63;
    if (wid >= 3 * BATCH_C) return;
    int s = wid >> 12;
    int j = wid & (BATCH_C - 1);
    int a = (s == 0) ? ua[j] : (s == 1) ? pa[j] : na[j];
    if (a != 4) return;                                // wave-uniform exit
    int idx0 = indexp[0];
    int row;
    if (s == 0)      row = users[j] + (idx0 ? N_USER_C : 0);
    else if (s == 1) row = pos[j]   + (idx0 ? 0 : N_USER_C);
    else             row = neg[j]   + (idx0 ? 0 : N_USER_C);
    int start = rs[row];
    int end   = rs[row + 1];
    int eo = lane >> 4;
    int l  = lane & 15;
    float4 acc = make_float4(0.f, 0.f, 0.f, 0.f);
    for (int it = start + eo; it < end; it += 4) {
        int2 p = ep[it];
        float v = __int_as_float(p.y);
        float4 g = ego[(int64_t)p.x * 16 + l];
        acc.x += v * g.x; acc.y += v * g.y; acc.z += v * g.z; acc.w += v * g.w;
    }
    acc.x += __shfl_xor(acc.x, 16); acc.y += __shfl_xor(acc.y, 16);
    acc.z += __shfl_xor(acc.z, 16); acc.w += __shfl_xor(acc.w, 16);
    acc.x += __shfl_xor(acc.x, 32); acc.y += __shfl_xor(acc.y, 32);
    acc.z += __shfl_xor(acc.z, 32); acc.w += __shfl_xor(acc.w, 32);
    if (lane < 16) {
        float4* o = (float4*)out + (int64_t)wid * 16 + l;
        float4 cv = *o;
        cv.x += acc.x; cv.y += acc.y; cv.z += acc.z; cv.w += acc.w;
        *o = cv;
    }
}

// ---------------- gather-accumulate the batch rows for hop `hop` ----------------
__global__ __launch_bounds__(256) void k_gather(const float* __restrict__ srcU,
                                                const float* __restrict__ srcI,
                                                int pivot,
                                                float* __restrict__ out,
                                                const int* __restrict__ users,
                                                const int* __restrict__ pos,
                                                const int* __restrict__ neg,
                                                const int* __restrict__ ua,
                                                const int* __restrict__ pa,
                                                const int* __restrict__ na,
                                                const int* __restrict__ indexp,
                                                int hop, int init) {
    int t = blockIdx.x * blockDim.x + threadIdx.x;
    if (t >= 3 * BATCH_C * EMB_C) return;
    int d = t & 63;
    int b = t >> 6;            // 0 .. 3*BATCH-1
    int s = b >> 12;           // 0=u, 1=p, 2=n   (BATCH=4096)
    int j = b & (BATCH_C - 1);
    int idx0 = indexp[0];
    int row, a;
    if (s == 0)      { row = users[j] + (idx0 ? N_USER_C : 0); a = ua[j]; }
    else if (s == 1) { row = pos[j]   + (idx0 ? 0 : N_USER_C); a = pa[j]; }
    else             { row = neg[j]   + (idx0 ? 0 : N_USER_C); a = na[j]; }
    if (hop <= a) {
        const float* sp = (row < pivot) ? (srcU + (int64_t)row * EMB_C)
                                        : (srcI + (int64_t)(row - pivot) * EMB_C);
        float x = sp[d];
        if (init) out[t] = x;
        else      out[t] += x;
    } else if (init) {
        out[t] = 0.0f;
    }
}

// ---------------- divide by (a+1) ----------------
__global__ __launch_bounds__(256) void k_scale(float* __restrict__ out,
                                               const int* __restrict__ ua,
                                               const int* __restrict__ pa,
                                               const int* __restrict__ na) {
    int t = blockIdx.x * blockDim.x + threadIdx.x;
    if (t >= 3 * BATCH_C * EMB_C) return;
    int b = t >> 6;
    int s = b >> 12;
    int j = b & (BATCH_C - 1);
    int a = (s == 0) ? ua[j] : (s == 1) ? pa[j] : na[j];
    out[t] /= (float)(a + 1);
}

extern "C" void kernel_launch(void* const* d_in, const int* in_sizes, int n_in,
                              void* d_out, int out_size, void* d_ws, size_t ws_size,
                              hipStream_t stream) {
    const float* user_emb = (const float*)d_in[0];
    const float* item_emb = (const float*)d_in[1];
    const float* adj_vals = (const float*)d_in[2];
    const float* drop_u   = (const float*)d_in[3];
    const int*   adj_rows = (const int*)d_in[4];
    const int*   adj_cols = (const int*)d_in[5];
    const int*   users    = (const int*)d_in[6];
    const int*   pos_it   = (const int*)d_in[7];
    const int*   neg_it   = (const int*)d_in[8];
    const int*   u_a      = (const int*)d_in[9];
    const int*   p_a      = (const int*)d_in[10];
    const int*   n_a      = (const int*)d_in[11];
    const int*   indexp   = (const int*)d_in[12];
    float* out = (float*)d_out;

    // workspace layout
    const size_t egoElems = (size_t)N_NODES_C * EMB_C;       // 9.6M floats
    float* bufA      = (float*)d_ws;                         // 38.4 MB
    float* bufB      = bufA + egoElems;                      // 38.4 MB
    int2*  ep        = (int2*)(bufB + egoElems);             // 9.6 MB (final CSR payload)
    int*   row_start = (int*)(ep + NNZ_C);                   // 600 KB (+sentinel)
    int*   cnt2      = row_start + N_NODES_C + 1;            // ~172 KB
    int*   base2     = cnt2 + N2 + 1;                        // ~172 KB
    int*   btot      = base2 + N2 + 1;                       // ~1.2 KB
    int*   bbase     = btot + NB + 1;                        // ~1.2 KB
    // build temporaries aliased into bufB (free until hop-2 output)
    int2*  ev        = (int2*)bufB;                          // 9.6 MB
    int*   er        = (int*)(ev + NNZ_C);                   // 4.8 MB

    // ---- CSR build: bucketed counting sort, all randomness L2-confined ----
    k_bin_count<<<NBLK, 1024, 0, stream>>>(drop_u, adj_rows, cnt2);
    k_btot<<<NB, 256, 0, stream>>>(cnt2, btot);
    k_bbase<<<1, 512, 0, stream>>>(btot, bbase, base2, row_start);
    k_bscan<<<NB, 256, 0, stream>>>(cnt2, bbase, base2);
    k_bin_write<<<NBLK, 1024, 0, stream>>>(adj_vals, drop_u, adj_rows, adj_cols,
                                           base2, ev, er);
    k_bucket_sort<<<NB, 256, 0, stream>>>(ev, er, base2, ep, row_start);

    // ---- hop-0 gather straight from the embedding tables ----
    const int GT = 3 * BATCH_C * EMB_C;
    k_gather<<<(GT + 255) / 256, 256, 0, stream>>>(user_emb, item_emb, N_USER_C, out,
                                                   users, pos_it, neg_it,
                                                   u_a, p_a, n_a, indexp, 0, 1);

    // ---- SpMM hops; hop 4 fused into the gather (only a==4 rows) ----
    const int SPMM_BLOCKS = (N_NODES_C * 64 + 255) / 256;    // one wave per row
    // hop 1: read directly from (user_emb, item_emb)
    k_spmm<<<SPMM_BLOCKS, 256, 0, stream>>>(row_start, ep,
                                            (const float4*)user_emb,
                                            (const float4*)item_emb, N_USER_C, bufA);
    k_gather<<<(GT + 255) / 256, 256, 0, stream>>>(bufA, bufA, N_NODES_C, out,
                                                   users, pos_it, neg_it,
                                                   u_a, p_a, n_a, indexp, 1, 0);
    // hop 2: bufA -> bufB
    k_spmm<<<SPMM_BLOCKS, 256, 0, stream>>>(row_start, ep,
                                            (const float4*)bufA, (const float4*)bufA,
                                            N_NODES_C, bufB);
    k_gather<<<(GT + 255) / 256, 256, 0, stream>>>(bufB, bufB, N_NODES_C, out,
                                                   users, pos_it, neg_it,
                                                   u_a, p_a, n_a, indexp, 2, 0);
    // hop 3: bufB -> bufA
    k_spmm<<<SPMM_BLOCKS, 256, 0, stream>>>(row_start, ep,
                                            (const float4*)bufB, (const float4*)bufB,
                                            N_NODES_C, bufA);
    k_gather<<<(GT + 255) / 256, 256, 0, stream>>>(bufA, bufA, N_NODES_C, out,
                                                   users, pos_it, neg_it,
                                                   u_a, p_a, n_a, indexp, 3, 0);
    // hop 4: fused sparse row-dot + accumulate, only where a==4
    k_spmm_g4<<<(3 * BATCH_C * 64 + 255) / 256, 256, 0, stream>>>(
        row_start, ep, (const float4*)bufA, out,
        users, pos_it, neg_it, u_a, p_a, n_a, indexp);

    // ---- final divide by (a+1) ----
    k_scale<<<(GT + 255) / 256, 256, 0, stream>>>(out, u_a, p_a, n_a);
}

// Round 6
// 226.512 us; speedup vs baseline: 4.6541x; 1.0416x over previous
//
#include <hip/hip_runtime.h>
#include <stdint.h>

#define N_USER_C  50000
#define N_ITEM_C  100000
#define N_NODES_C 150000
#define EMB_C     64
#define NNZ_C     1200000
#define BATCH_C   4096

#define BKT_SHIFT 9                                   // 512 rows per bucket
#define BKT_ROWS  (1 << BKT_SHIFT)
#define NB        ((N_NODES_C + BKT_ROWS - 1) / BKT_ROWS)   // 293
#define CH        8192                                // edges per binning block
#define NBLK      ((NNZ_C + CH - 1) / CH)             // 147
#define N2        (NB * NBLK)                         // 43071

typedef _Float16 h16;
typedef _Float16 h16x4 __attribute__((ext_vector_type(4)));

// ---------------- pass A: per-(block,bucket) histogram of kept edges ----------------
__global__ __launch_bounds__(1024) void k_bin_count(const float* __restrict__ du,
                                                    const int* __restrict__ rows,
                                                    int* __restrict__ cnt2) {
    __shared__ int bk[NB];
    int t = threadIdx.x, blk = blockIdx.x;
    for (int i = t; i < NB; i += 1024) bk[i] = 0;
    __syncthreads();
    int base = blk * CH;
    for (int i = 0; i < CH; i += 1024) {
        int e = base + i + t;
        if (e < NNZ_C && floorf(0.9f + du[e]) != 0.0f)
            atomicAdd(&bk[rows[e] >> BKT_SHIFT], 1);
    }
    __syncthreads();
    for (int i = t; i < NB; i += 1024) cnt2[i * NBLK + blk] = bk[i];
}

// ---------------- pass B1: per-bucket totals ----------------
__global__ __launch_bounds__(256) void k_btot(const int* __restrict__ cnt2,
                                              int* __restrict__ btot) {
    __shared__ int red[256];
    int t = threadIdx.x, i = blockIdx.x;
    red[t] = (t < NBLK) ? cnt2[i * NBLK + t] : 0;
    __syncthreads();
    for (int off = 128; off > 0; off >>= 1) {
        if (t < off) red[t] += red[t + off];
        __syncthreads();
    }
    if (t == 0) btot[i] = red[0];
}

// ---------------- pass B2: scan of 293 bucket totals ----------------
__global__ __launch_bounds__(512) void k_bbase(const int* __restrict__ btot,
                                               int* __restrict__ bbase,
                                               int* __restrict__ base2,
                                               int* __restrict__ row_start) {
    __shared__ int sh[512];
    int t = threadIdx.x;
    int v0 = (t < NB) ? btot[t] : 0;
    sh[t] = v0;
    __syncthreads();
    for (int off = 1; off < 512; off <<= 1) {
        int v = (t >= off) ? sh[t - off] : 0;
        __syncthreads();
        sh[t] += v;
        __syncthreads();
    }
    if (t < NB) bbase[t] = sh[t] - v0;                 // exclusive bucket prefix
    if (t == 511) {
        base2[N2] = sh[511];                           // total kept edges
        row_start[N_NODES_C] = sh[511];                // CSR sentinel
    }
}

// ---------------- pass B3: per-bucket scan of 147 block counts ----------------
__global__ __launch_bounds__(256) void k_bscan(const int* __restrict__ cnt2,
                                               const int* __restrict__ bbase,
                                               int* __restrict__ base2) {
    __shared__ int sh[256];
    int t = threadIdx.x, i = blockIdx.x;
    int v0 = (t < NBLK) ? cnt2[i * NBLK + t] : 0;
    sh[t] = v0;
    __syncthreads();
    for (int off = 1; off < 256; off <<= 1) {
        int v = (t >= off) ? sh[t - off] : 0;
        __syncthreads();
        sh[t] += v;
        __syncthreads();
    }
    if (t < NBLK) base2[i * NBLK + t] = bbase[i] + sh[t] - v0;
}

// ---------------- pass C: bucket-sorted write of (col,val) + row ----------------
__global__ __launch_bounds__(1024) void k_bin_write(const float* __restrict__ av,
                                                    const float* __restrict__ du,
                                                    const int* __restrict__ rows,
                                                    const int* __restrict__ cols,
                                                    const int* __restrict__ base2,
                                                    int2* __restrict__ ev,
                                                    int* __restrict__ er) {
    __shared__ int cur[NB];
    int t = threadIdx.x, blk = blockIdx.x;
    for (int i = t; i < NB; i += 1024) cur[i] = base2[i * NBLK + blk];
    __syncthreads();
    int base = blk * CH;
    for (int i = 0; i < CH; i += 1024) {
        int e = base + i + t;
        if (e < NNZ_C) {
            float m = floorf(0.9f + du[e]);
            if (m != 0.0f) {
                float v = av[e] * m * (float)(1.0 / 0.9);
                int r = rows[e];
                int pos = atomicAdd(&cur[r >> BKT_SHIFT], 1);
                int2 p; p.x = cols[e]; p.y = __float_as_int(v);
                ev[pos] = p;
                er[pos] = r;
            }
        }
    }
}

// ---------------- pass D: per-bucket exact row sort (LDS hist+scan+scatter) ----------------
__global__ __launch_bounds__(256) void k_bucket_sort(const int2* __restrict__ ev,
                                                     const int* __restrict__ er,
                                                     const int* __restrict__ base2,
                                                     int2* __restrict__ ep,
                                                     int* __restrict__ row_start) {
    __shared__ int rowcnt[BKT_ROWS];
    __shared__ int cursor[BKT_ROWS];
    __shared__ int tsum[256];
    int t = threadIdx.x, k = blockIdx.x;
    int rowBase = k << BKT_SHIFT;
    int bstart = base2[k * NBLK];
    int bend   = base2[(k + 1) * NBLK];               // k=NB-1 hits base2[N2]=total
    for (int i = t; i < BKT_ROWS; i += 256) rowcnt[i] = 0;
    __syncthreads();
    for (int e = bstart + t; e < bend; e += 256)
        atomicAdd(&rowcnt[er[e] - rowBase], 1);
    __syncthreads();
    int a = rowcnt[2 * t], b = rowcnt[2 * t + 1];
    tsum[t] = a + b;
    __syncthreads();
    for (int off = 1; off < 256; off <<= 1) {
        int v = (t >= off) ? tsum[t - off] : 0;
        __syncthreads();
        tsum[t] += v;
        __syncthreads();
    }
    int excl = tsum[t] - (a + b);
    cursor[2 * t]     = excl;
    cursor[2 * t + 1] = excl + a;
    int gr = rowBase + 2 * t;
    if (gr < N_NODES_C)     row_start[gr]     = bstart + excl;
    if (gr + 1 < N_NODES_C) row_start[gr + 1] = bstart + excl + a;
    __syncthreads();
    for (int e = bstart + t; e < bend; e += 256) {
        int r = er[e];
        int slot = atomicAdd(&cursor[r - rowBase], 1);
        ep[bstart + slot] = ev[e];
    }
}

// ---------------- one-time f32 tables -> fp16 ego0 ----------------
__global__ __launch_bounds__(256) void k_tohalf(const float4* __restrict__ ue,
                                                const float4* __restrict__ ie,
                                                h16x4* __restrict__ dst) {
    const int totalU = N_USER_C * EMB_C / 4;          // 800k float4s
    const int total  = N_NODES_C * EMB_C / 4;         // 2.4M float4s
    int stride = gridDim.x * blockDim.x;
    for (int i = blockIdx.x * blockDim.x + threadIdx.x; i < total; i += stride) {
        float4 v = (i < totalU) ? ue[i] : ie[i - totalU];
        h16x4 h;
        h[0] = (h16)v.x; h[1] = (h16)v.y; h[2] = (h16)v.z; h[3] = (h16)v.w;
        dst[i] = h;
    }
}

// ---------------- CSR SpMM (fp16 ego): one wave per row, 4 edges x 16 lane-quads ----------------
__global__ __launch_bounds__(256) void k_spmm_h(const int* __restrict__ rs,
                                                const int2* __restrict__ ep,
                                                const h16x4* __restrict__ ego,
                                                h16x4* __restrict__ nxt) {
    int wid  = (blockIdx.x * blockDim.x + threadIdx.x) >> 6;   // one wave per row
    int lane = threadIdx.x & 63;
    if (wid >= N_NODES_C) return;
    int start = rs[wid];
    int end   = rs[wid + 1];
    int eo = lane >> 4;          // edge slot 0..3
    int l  = lane & 15;          // h16x4 index within the 64-half row
    float4 acc = make_float4(0.f, 0.f, 0.f, 0.f);
    #pragma unroll 2
    for (int it = start + eo; it < end; it += 4) {
        int2 p = ep[it];
        float v = __int_as_float(p.y);
        h16x4 g = ego[(int64_t)p.x * 16 + l];          // 128B coalesced row gather
        acc.x += v * (float)g[0]; acc.y += v * (float)g[1];
        acc.z += v * (float)g[2]; acc.w += v * (float)g[3];
    }
    acc.x += __shfl_xor(acc.x, 16); acc.y += __shfl_xor(acc.y, 16);
    acc.z += __shfl_xor(acc.z, 16); acc.w += __shfl_xor(acc.w, 16);
    acc.x += __shfl_xor(acc.x, 32); acc.y += __shfl_xor(acc.y, 32);
    acc.z += __shfl_xor(acc.z, 32); acc.w += __shfl_xor(acc.w, 32);
    if (lane < 16) {
        h16x4 h;
        h[0] = (h16)acc.x; h[1] = (h16)acc.y; h[2] = (h16)acc.z; h[3] = (h16)acc.w;
        nxt[(int64_t)wid * 16 + l] = h;
    }
}

// ---------------- fused hop-4: per batch entry with a==4, one wave CSR dot -> out ----------------
__global__ __launch_bounds__(256) void k_spmm_g4(const int* __restrict__ rs,
                                                 const int2* __restrict__ ep,
                                                 const h16x4* __restrict__ ego,
                                                 float* __restrict__ out,
                                                 const int* __restrict__ users,
                                                 const int* __restrict__ pos,
                                                 const int* __restrict__ neg,
                                                 const int* __restrict__ ua,
                                                 const int* __restrict__ pa,
                                                 const int* __restrict__ na,
                                                 const int* __restrict__ indexp) {
    int wid  = (blockIdx.x * blockDim.x + threadIdx.x) >> 6;   // batch slot 0..3*BATCH-1
    int lane = threadIdx.x & 63;
    if (wid >= 3 * BATCH_C) return;
    int s = wid >> 12;
    int j = wid & (BATCH_C - 1);
    int a = (s == 0) ? ua[j] : (s == 1) ? pa[j] : na[j];
    if (a != 4) return;                                // wave-uniform exit
    int idx0 = indexp[0];
    int row;
    if (s == 0)      row = users[j] + (idx0 ? N_USER_C : 0);
    else if (s == 1) row = pos[j]   + (idx0 ? 0 : N_USER_C);
    else             row = neg[j]   + (idx0 ? 0 : N_USER_C);
    int start = rs[row];
    int end   = rs[row + 1];
    int eo = lane >> 4;
    int l  = lane & 15;
    float4 acc = make_float4(0.f, 0.f, 0.f, 0.f);
    for (int it = start + eo; it < end; it += 4) {
        int2 p = ep[it];
        float v = __int_as_float(p.y);
        h16x4 g = ego[(int64_t)p.x * 16 + l];
        acc.x += v * (float)g[0]; acc.y += v * (float)g[1];
        acc.z += v * (float)g[2]; acc.w += v * (float)g[3];
    }
    acc.x += __shfl_xor(acc.x, 16); acc.y += __shfl_xor(acc.y, 16);
    acc.z += __shfl_xor(acc.z, 16); acc.w += __shfl_xor(acc.w, 16);
    acc.x += __shfl_xor(acc.x, 32); acc.y += __shfl_xor(acc.y, 32);
    acc.z += __shfl_xor(acc.z, 32); acc.w += __shfl_xor(acc.w, 32);
    if (lane < 16) {
        float4* o = (float4*)out + (int64_t)wid * 16 + l;
        float4 cv = *o;
        cv.x += acc.x; cv.y += acc.y; cv.z += acc.z; cv.w += acc.w;
        *o = cv;
    }
}

// ---------------- hop-0 gather from the f32 tables (init) ----------------
__global__ __launch_bounds__(256) void k_gather(const float* __restrict__ srcU,
                                                const float* __restrict__ srcI,
                                                int pivot,
                                                float* __restrict__ out,
                                                const int* __restrict__ users,
                                                const int* __restrict__ pos,
                                                const int* __restrict__ neg,
                                                const int* __restrict__ ua,
                                                const int* __restrict__ pa,
                                                const int* __restrict__ na,
                                                const int* __restrict__ indexp) {
    int t = blockIdx.x * blockDim.x + threadIdx.x;
    if (t >= 3 * BATCH_C * EMB_C) return;
    int d = t & 63;
    int b = t >> 6;            // 0 .. 3*BATCH-1
    int s = b >> 12;           // 0=u, 1=p, 2=n   (BATCH=4096)
    int j = b & (BATCH_C - 1);
    int idx0 = indexp[0];
    int row;
    if (s == 0)      row = users[j] + (idx0 ? N_USER_C : 0);
    else if (s == 1) row = pos[j]   + (idx0 ? 0 : N_USER_C);
    else             row = neg[j]   + (idx0 ? 0 : N_USER_C);
    const float* sp = (row < pivot) ? (srcU + (int64_t)row * EMB_C)
                                    : (srcI + (int64_t)(row - pivot) * EMB_C);
    out[t] = sp[d];
}

// ---------------- fp16 gather-accumulate for hops 1..3 ----------------
__global__ __launch_bounds__(256) void k_gather_h(const h16* __restrict__ src,
                                                  float* __restrict__ out,
                                                  const int* __restrict__ users,
                                                  const int* __restrict__ pos,
                                                  const int* __restrict__ neg,
                                                  const int* __restrict__ ua,
                                                  const int* __restrict__ pa,
                                                  const int* __restrict__ na,
                                                  const int* __restrict__ indexp,
                                                  int hop) {
    int t = blockIdx.x * blockDim.x + threadIdx.x;
    if (t >= 3 * BATCH_C * EMB_C) return;
    int d = t & 63;
    int b = t >> 6;
    int s = b >> 12;
    int j = b & (BATCH_C - 1);
    int idx0 = indexp[0];
    int row, a;
    if (s == 0)      { row = users[j] + (idx0 ? N_USER_C : 0); a = ua[j]; }
    else if (s == 1) { row = pos[j]   + (idx0 ? 0 : N_USER_C); a = pa[j]; }
    else             { row = neg[j]   + (idx0 ? 0 : N_USER_C); a = na[j]; }
    if (hop <= a)
        out[t] += (float)src[(int64_t)row * EMB_C + d];
}

// ---------------- divide by (a+1) ----------------
__global__ __launch_bounds__(256) void k_scale(float* __restrict__ out,
                                               const int* __restrict__ ua,
                                               const int* __restrict__ pa,
                                               const int* __restrict__ na) {
    int t = blockIdx.x * blockDim.x + threadIdx.x;
    if (t >= 3 * BATCH_C * EMB_C) return;
    int b = t >> 6;
    int s = b >> 12;
    int j = b & (BATCH_C - 1);
    int a = (s == 0) ? ua[j] : (s == 1) ? pa[j] : na[j];
    out[t] /= (float)(a + 1);
}

extern "C" void kernel_launch(void* const* d_in, const int* in_sizes, int n_in,
                              void* d_out, int out_size, void* d_ws, size_t ws_size,
                              hipStream_t stream) {
    const float* user_emb = (const float*)d_in[0];
    const float* item_emb = (const float*)d_in[1];
    const float* adj_vals = (const float*)d_in[2];
    const float* drop_u   = (const float*)d_in[3];
    const int*   adj_rows = (const int*)d_in[4];
    const int*   adj_cols = (const int*)d_in[5];
    const int*   users    = (const int*)d_in[6];
    const int*   pos_it   = (const int*)d_in[7];
    const int*   neg_it   = (const int*)d_in[8];
    const int*   u_a      = (const int*)d_in[9];
    const int*   p_a      = (const int*)d_in[10];
    const int*   n_a      = (const int*)d_in[11];
    const int*   indexp   = (const int*)d_in[12];
    float* out = (float*)d_out;

    // workspace layout (no aliasing; ~83 MB total)
    const size_t egoElems = (size_t)N_NODES_C * EMB_C;       // 9.6M
    h16*   egoH0     = (h16*)d_ws;                           // 19.2 MB
    h16*   bufA      = egoH0 + egoElems;                     // 19.2 MB
    h16*   bufB      = bufA + egoElems;                      // 19.2 MB
    int2*  ep        = (int2*)(bufB + egoElems);             // 9.6 MB (final CSR)
    int2*  ev        = ep + NNZ_C;                           // 9.6 MB (build tmp)
    int*   er        = (int*)(ev + NNZ_C);                   // 4.8 MB (build tmp)
    int*   row_start = er + NNZ_C;                           // 600 KB (+sentinel)
    int*   cnt2      = row_start + N_NODES_C + 1;            // ~172 KB
    int*   base2     = cnt2 + N2 + 1;                        // ~172 KB
    int*   btot      = base2 + N2 + 1;                       // ~1.2 KB
    int*   bbase     = btot + NB + 1;                        // ~1.2 KB

    // ---- CSR build: bucketed counting sort, all randomness L2-confined ----
    k_bin_count<<<NBLK, 1024, 0, stream>>>(drop_u, adj_rows, cnt2);
    k_btot<<<NB, 256, 0, stream>>>(cnt2, btot);
    k_bbase<<<1, 512, 0, stream>>>(btot, bbase, base2, row_start);
    k_bscan<<<NB, 256, 0, stream>>>(cnt2, bbase, base2);
    k_bin_write<<<NBLK, 1024, 0, stream>>>(adj_vals, drop_u, adj_rows, adj_cols,
                                           base2, ev, er);
    k_bucket_sort<<<NB, 256, 0, stream>>>(ev, er, base2, ep, row_start);

    // ---- fp16 ego0 + hop-0 gather ----
    k_tohalf<<<2048, 256, 0, stream>>>((const float4*)user_emb,
                                       (const float4*)item_emb, (h16x4*)egoH0);
    const int GT = 3 * BATCH_C * EMB_C;
    k_gather<<<(GT + 255) / 256, 256, 0, stream>>>(user_emb, item_emb, N_USER_C, out,
                                                   users, pos_it, neg_it,
                                                   u_a, p_a, n_a, indexp);

    // ---- SpMM hops (fp16 ego); hop 4 fused into the gather (only a==4 rows) ----
    const int SPMM_BLOCKS = (N_NODES_C * 64 + 255) / 256;    // one wave per row
    k_spmm_h<<<SPMM_BLOCKS, 256, 0, stream>>>(row_start, ep, (const h16x4*)egoH0,
                                              (h16x4*)bufA);
    k_gather_h<<<(GT + 255) / 256, 256, 0, stream>>>(bufA, out, users, pos_it, neg_it,
                                                     u_a, p_a, n_a, indexp, 1);
    k_spmm_h<<<SPMM_BLOCKS, 256, 0, stream>>>(row_start, ep, (const h16x4*)bufA,
                                              (h16x4*)bufB);
    k_gather_h<<<(GT + 255) / 256, 256, 0, stream>>>(bufB, out, users, pos_it, neg_it,
                                                     u_a, p_a, n_a, indexp, 2);
    k_spmm_h<<<SPMM_BLOCKS, 256, 0, stream>>>(row_start, ep, (const h16x4*)bufB,
                                              (h16x4*)bufA);
    k_gather_h<<<(GT + 255) / 256, 256, 0, stream>>>(bufA, out, users, pos_it, neg_it,
                                                     u_a, p_a, n_a, indexp, 3);
    k_spmm_g4<<<(3 * BATCH_C * 64 + 255) / 256, 256, 0, stream>>>(
        row_start, ep, (const h16x4*)bufA, out,
        users, pos_it, neg_it, u_a, p_a, n_a, indexp);

    // ---- final divide by (a+1) ----
    k_scale<<<(GT + 255) / 256, 256, 0, stream>>>(out, u_a, p_a, n_a);
}

// Round 7
// 203.313 us; speedup vs baseline: 5.1852x; 1.1141x over previous
//
#include <hip/hip_runtime.h>
#include <stdint.h>

#define N_USER_C  50000
#define N_ITEM_C  100000
#define N_NODES_C 150000
#define EMB_C     64
#define NNZ_C     1200000
#define BATCH_C   4096

#define BKT_SHIFT 9                                   // 512 rows per bucket
#define BKT_ROWS  (1 << BKT_SHIFT)
#define NB        ((N_NODES_C + BKT_ROWS - 1) / BKT_ROWS)   // 293
#define CH        8192                                // edges per binning block
#define NBLK      ((NNZ_C + CH - 1) / CH)             // 147
#define N2        (NB * NBLK)                         // 43071
#define COL_MASK  0x3FFFF                             // 18 bits (N_NODES < 2^18)

typedef _Float16 h16;
typedef _Float16 h16x4 __attribute__((ext_vector_type(4)));
typedef _Float16 h16x8 __attribute__((ext_vector_type(8)));

// ---------------- pass A: per-(block,bucket) histogram of kept edges ----------------
__global__ __launch_bounds__(1024) void k_bin_count(const float* __restrict__ du,
                                                    const int* __restrict__ rows,
                                                    int* __restrict__ cnt2) {
    __shared__ int bk[NB];
    int t = threadIdx.x, blk = blockIdx.x;
    for (int i = t; i < NB; i += 1024) bk[i] = 0;
    __syncthreads();
    int base = blk * CH;
    for (int i = 0; i < CH; i += 1024) {
        int e = base + i + t;
        if (e < NNZ_C && floorf(0.9f + du[e]) != 0.0f)
            atomicAdd(&bk[rows[e] >> BKT_SHIFT], 1);
    }
    __syncthreads();
    for (int i = t; i < NB; i += 1024) cnt2[i * NBLK + blk] = bk[i];
}

// ---------------- pass B1: per-bucket totals ----------------
__global__ __launch_bounds__(256) void k_btot(const int* __restrict__ cnt2,
                                              int* __restrict__ btot) {
    __shared__ int red[256];
    int t = threadIdx.x, i = blockIdx.x;
    red[t] = (t < NBLK) ? cnt2[i * NBLK + t] : 0;
    __syncthreads();
    for (int off = 128; off > 0; off >>= 1) {
        if (t < off) red[t] += red[t + off];
        __syncthreads();
    }
    if (t == 0) btot[i] = red[0];
}

// ---------------- pass B2: scan of 293 bucket totals ----------------
__global__ __launch_bounds__(512) void k_bbase(const int* __restrict__ btot,
                                               int* __restrict__ bbase,
                                               int* __restrict__ base2,
                                               int* __restrict__ row_start) {
    __shared__ int sh[512];
    int t = threadIdx.x;
    int v0 = (t < NB) ? btot[t] : 0;
    sh[t] = v0;
    __syncthreads();
    for (int off = 1; off < 512; off <<= 1) {
        int v = (t >= off) ? sh[t - off] : 0;
        __syncthreads();
        sh[t] += v;
        __syncthreads();
    }
    if (t < NB) bbase[t] = sh[t] - v0;                 // exclusive bucket prefix
    if (t == 511) {
        base2[N2] = sh[511];                           // total kept edges
        row_start[N_NODES_C] = sh[511];                // CSR sentinel
    }
}

// ---------------- pass B3: per-bucket scan of 147 block counts ----------------
__global__ __launch_bounds__(256) void k_bscan(const int* __restrict__ cnt2,
                                               const int* __restrict__ bbase,
                                               int* __restrict__ base2) {
    __shared__ int sh[256];
    int t = threadIdx.x, i = blockIdx.x;
    int v0 = (t < NBLK) ? cnt2[i * NBLK + t] : 0;
    sh[t] = v0;
    __syncthreads();
    for (int off = 1; off < 256; off <<= 1) {
        int v = (t >= off) ? sh[t - off] : 0;
        __syncthreads();
        sh[t] += v;
        __syncthreads();
    }
    if (t < NBLK) base2[i * NBLK + t] = bbase[i] + sh[t] - v0;
}

// ---------------- pass C: bucket-sorted write of packed (rl|col, val) ----------------
__global__ __launch_bounds__(1024) void k_bin_write(const float* __restrict__ av,
                                                    const float* __restrict__ du,
                                                    const int* __restrict__ rows,
                                                    const int* __restrict__ cols,
                                                    const int* __restrict__ base2,
                                                    int2* __restrict__ ev) {
    __shared__ int cur[NB];
    int t = threadIdx.x, blk = blockIdx.x;
    for (int i = t; i < NB; i += 1024) cur[i] = base2[i * NBLK + blk];
    __syncthreads();
    int base = blk * CH;
    for (int i = 0; i < CH; i += 1024) {
        int e = base + i + t;
        if (e < NNZ_C) {
            float m = floorf(0.9f + du[e]);
            if (m != 0.0f) {
                float v = av[e] * m * (float)(1.0 / 0.9);
                int r = rows[e];
                int pos = atomicAdd(&cur[r >> BKT_SHIFT], 1);
                int2 p;
                p.x = ((r & (BKT_ROWS - 1)) << 18) | cols[e];   // rl:9 | col:18
                p.y = __float_as_int(v);
                ev[pos] = p;
            }
        }
    }
}

// ---------------- pass D: per-bucket exact row sort (LDS hist+scan+scatter) ----------------
__global__ __launch_bounds__(256) void k_bucket_sort(const int2* __restrict__ ev,
                                                     const int* __restrict__ base2,
                                                     int2* __restrict__ ep,
                                                     int* __restrict__ row_start) {
    __shared__ int rowcnt[BKT_ROWS];
    __shared__ int cursor[BKT_ROWS];
    __shared__ int tsum[256];
    int t = threadIdx.x, k = blockIdx.x;
    int rowBase = k << BKT_SHIFT;
    int bstart = base2[k * NBLK];
    int bend   = base2[(k + 1) * NBLK];               // k=NB-1 hits base2[N2]=total
    for (int i = t; i < BKT_ROWS; i += 256) rowcnt[i] = 0;
    __syncthreads();
    for (int e = bstart + t; e < bend; e += 256)
        atomicAdd(&rowcnt[((unsigned)ev[e].x) >> 18], 1);
    __syncthreads();
    int a = rowcnt[2 * t], b = rowcnt[2 * t + 1];
    tsum[t] = a + b;
    __syncthreads();
    for (int off = 1; off < 256; off <<= 1) {
        int v = (t >= off) ? tsum[t - off] : 0;
        __syncthreads();
        tsum[t] += v;
        __syncthreads();
    }
    int excl = tsum[t] - (a + b);
    cursor[2 * t]     = excl;
    cursor[2 * t + 1] = excl + a;
    int gr = rowBase + 2 * t;
    if (gr < N_NODES_C)     row_start[gr]     = bstart + excl;
    if (gr + 1 < N_NODES_C) row_start[gr + 1] = bstart + excl + a;
    __syncthreads();
    for (int e = bstart + t; e < bend; e += 256) {
        int2 p = ev[e];
        int rl = ((unsigned)p.x) >> 18;
        int slot = atomicAdd(&cursor[rl], 1);
        p.x &= COL_MASK;                               // strip rl -> clean col
        ep[bstart + slot] = p;
    }
}

// ---------------- one-time f32 tables -> fp16 ego0 ----------------
__global__ __launch_bounds__(256) void k_tohalf(const float4* __restrict__ ue,
                                                const float4* __restrict__ ie,
                                                h16x4* __restrict__ dst) {
    const int totalU = N_USER_C * EMB_C / 4;          // 800k float4s
    const int total  = N_NODES_C * EMB_C / 4;         // 2.4M float4s
    int stride = gridDim.x * blockDim.x;
    for (int i = blockIdx.x * blockDim.x + threadIdx.x; i < total; i += stride) {
        float4 v = (i < totalU) ? ue[i] : ie[i - totalU];
        h16x4 h;
        h[0] = (h16)v.x; h[1] = (h16)v.y; h[2] = (h16)v.z; h[3] = (h16)v.w;
        dst[i] = h;
    }
}

// ---------------- CSR SpMM: one wave per row, 8 edge slots x 8 lanes x 16B ----------------
// Preloads up to 64 ep entries coalesced, broadcasts col/val via shuffle.
// Optional row flag (nullptr = compute all rows).
__global__ __launch_bounds__(256) void k_spmm8(const int* __restrict__ rs,
                                               const int2* __restrict__ ep,
                                               const h16x8* __restrict__ ego,
                                               h16x8* __restrict__ nxt,
                                               const int* __restrict__ flag) {
    int wid  = (blockIdx.x * blockDim.x + threadIdx.x) >> 6;   // one wave per row
    int lane = threadIdx.x & 63;
    if (wid >= N_NODES_C) return;
    if (flag && flag[wid] == 0) return;                // wave-uniform early exit
    int start = rs[wid];
    int end   = rs[wid + 1];
    int slot = lane >> 3;        // edge slot 0..7
    int q    = lane & 7;         // 16B segment within the 128B row
    float acc[8] = {0.f, 0.f, 0.f, 0.f, 0.f, 0.f, 0.f, 0.f};
    for (int base = start; base < end; base += 64) {
        int nw = end - base; if (nw > 64) nw = 64;
        int2 pe = ep[base + (lane < nw ? lane : nw - 1)];   // coalesced, 512B/wave
        int nr = (nw + 7) >> 3;
        for (int r = 0; r < nr; ++r) {
            int idx = r * 8 + slot;
            int   c = __shfl(pe.x, idx);
            float v = __int_as_float(__shfl(pe.y, idx));
            if (idx < nw) {
                h16x8 g = ego[(int64_t)c * 8 + q];          // 128B line per slot
                #pragma unroll
                for (int i = 0; i < 8; ++i) acc[i] += v * (float)g[i];
            }
        }
    }
    #pragma unroll
    for (int m = 8; m <= 32; m <<= 1) {
        #pragma unroll
        for (int i = 0; i < 8; ++i) acc[i] += __shfl_xor(acc[i], m);
    }
    if (lane < 8) {              // slot 0 holds the full sums
        h16x8 h;
        #pragma unroll
        for (int i = 0; i < 8; ++i) h[i] = (h16)acc[i];
        nxt[(int64_t)wid * 8 + q] = h;
    }
}

// ---------------- flag rows whose hop-3 value is needed ----------------
__global__ __launch_bounds__(256) void k_flags(const int* __restrict__ rs,
                                               const int2* __restrict__ ep,
                                               int* __restrict__ flag,
                                               const int* __restrict__ users,
                                               const int* __restrict__ pos,
                                               const int* __restrict__ neg,
                                               const int* __restrict__ ua,
                                               const int* __restrict__ pa,
                                               const int* __restrict__ na,
                                               const int* __restrict__ indexp) {
    int wid  = (blockIdx.x * blockDim.x + threadIdx.x) >> 6;   // batch slot
    int lane = threadIdx.x & 63;
    if (wid >= 3 * BATCH_C) return;
    int s = wid >> 12;
    int j = wid & (BATCH_C - 1);
    int a = (s == 0) ? ua[j] : (s == 1) ? pa[j] : na[j];
    if (a < 3) return;
    int idx0 = indexp[0];
    int row;
    if (s == 0)      row = users[j] + (idx0 ? N_USER_C : 0);
    else if (s == 1) row = pos[j]   + (idx0 ? 0 : N_USER_C);
    else             row = neg[j]   + (idx0 ? 0 : N_USER_C);
    if (lane == 0) flag[row] = 1;                      // hop-3 gathered for a>=3
    if (a == 4) {                                      // cols read by g4 from hop-3
        int start = rs[row], end = rs[row + 1];
        for (int e = start + lane; e < end; e += 64)
            flag[ep[e].x] = 1;                         // benign same-value races
    }
}

// ---------------- fused hop-4: per batch entry with a==4, one wave CSR dot -> out ----------------
__global__ __launch_bounds__(256) void k_spmm_g4(const int* __restrict__ rs,
                                                 const int2* __restrict__ ep,
                                                 const h16x4* __restrict__ ego,
                                                 float* __restrict__ out,
                                                 const int* __restrict__ users,
                                                 const int* __restrict__ pos,
                                                 const int* __restrict__ neg,
                                                 const int* __restrict__ ua,
                                                 const int* __restrict__ pa,
                                                 const int* __restrict__ na,
                                                 const int* __restrict__ indexp) {
    int wid  = (blockIdx.x * blockDim.x + threadIdx.x) >> 6;   // batch slot
    int lane = threadIdx.x & 63;
    if (wid >= 3 * BATCH_C) return;
    int s = wid >> 12;
    int j = wid & (BATCH_C - 1);
    int a = (s == 0) ? ua[j] : (s == 1) ? pa[j] : na[j];
    if (a != 4) return;                                // wave-uniform exit
    int idx0 = indexp[0];
    int row;
    if (s == 0)      row = users[j] + (idx0 ? N_USER_C : 0);
    else if (s == 1) row = pos[j]   + (idx0 ? 0 : N_USER_C);
    else             row = neg[j]   + (idx0 ? 0 : N_USER_C);
    int start = rs[row];
    int end   = rs[row + 1];
    int eo = lane >> 4;
    int l  = lane & 15;
    float4 acc = make_float4(0.f, 0.f, 0.f, 0.f);
    for (int it = start + eo; it < end; it += 4) {
        int2 p = ep[it];
        float v = __int_as_float(p.y);
        h16x4 g = ego[(int64_t)p.x * 16 + l];
        acc.x += v * (float)g[0]; acc.y += v * (float)g[1];
        acc.z += v * (float)g[2]; acc.w += v * (float)g[3];
    }
    acc.x += __shfl_xor(acc.x, 16); acc.y += __shfl_xor(acc.y, 16);
    acc.z += __shfl_xor(acc.z, 16); acc.w += __shfl_xor(acc.w, 16);
    acc.x += __shfl_xor(acc.x, 32); acc.y += __shfl_xor(acc.y, 32);
    acc.z += __shfl_xor(acc.z, 32); acc.w += __shfl_xor(acc.w, 32);
    if (lane < 16) {
        float4* o = (float4*)out + (int64_t)wid * 16 + l;
        float4 cv = *o;
        cv.x += acc.x; cv.y += acc.y; cv.z += acc.z; cv.w += acc.w;
        *o = cv;
    }
}

// ---------------- hop-0 gather from the f32 tables (init) ----------------
__global__ __launch_bounds__(256) void k_gather(const float* __restrict__ srcU,
                                                const float* __restrict__ srcI,
                                                int pivot,
                                                float* __restrict__ out,
                                                const int* __restrict__ users,
                                                const int* __restrict__ pos,
                                                const int* __restrict__ neg,
                                                const int* __restrict__ ua,
                                                const int* __restrict__ pa,
                                                const int* __restrict__ na,
                                                const int* __restrict__ indexp) {
    int t = blockIdx.x * blockDim.x + threadIdx.x;
    if (t >= 3 * BATCH_C * EMB_C) return;
    int d = t & 63;
    int b = t >> 6;            // 0 .. 3*BATCH-1
    int s = b >> 12;           // 0=u, 1=p, 2=n   (BATCH=4096)
    int j = b & (BATCH_C - 1);
    int idx0 = indexp[0];
    int row;
    if (s == 0)      row = users[j] + (idx0 ? N_USER_C : 0);
    else if (s == 1) row = pos[j]   + (idx0 ? 0 : N_USER_C);
    else             row = neg[j]   + (idx0 ? 0 : N_USER_C);
    const float* sp = (row < pivot) ? (srcU + (int64_t)row * EMB_C)
                                    : (srcI + (int64_t)(row - pivot) * EMB_C);
    out[t] = sp[d];
}

// ---------------- fp16 gather-accumulate for hops 1..3 ----------------
__global__ __launch_bounds__(256) void k_gather_h(const h16* __restrict__ src,
                                                  float* __restrict__ out,
                                                  const int* __restrict__ users,
                                                  const int* __restrict__ pos,
                                                  const int* __restrict__ neg,
                                                  const int* __restrict__ ua,
                                                  const int* __restrict__ pa,
                                                  const int* __restrict__ na,
                                                  const int* __restrict__ indexp,
                                                  int hop) {
    int t = blockIdx.x * blockDim.x + threadIdx.x;
    if (t >= 3 * BATCH_C * EMB_C) return;
    int d = t & 63;
    int b = t >> 6;
    int s = b >> 12;
    int j = b & (BATCH_C - 1);
    int idx0 = indexp[0];
    int row, a;
    if (s == 0)      { row = users[j] + (idx0 ? N_USER_C : 0); a = ua[j]; }
    else if (s == 1) { row = pos[j]   + (idx0 ? 0 : N_USER_C); a = pa[j]; }
    else             { row = neg[j]   + (idx0 ? 0 : N_USER_C); a = na[j]; }
    if (hop <= a)
        out[t] += (float)src[(int64_t)row * EMB_C + d];
}

// ---------------- divide by (a+1) ----------------
__global__ __launch_bounds__(256) void k_scale(float* __restrict__ out,
                                               const int* __restrict__ ua,
                                               const int* __restrict__ pa,
                                               const int* __restrict__ na) {
    int t = blockIdx.x * blockDim.x + threadIdx.x;
    if (t >= 3 * BATCH_C * EMB_C) return;
    int b = t >> 6;
    int s = b >> 12;
    int j = b & (BATCH_C - 1);
    int a = (s == 0) ? ua[j] : (s == 1) ? pa[j] : na[j];
    out[t] /= (float)(a + 1);
}

extern "C" void kernel_launch(void* const* d_in, const int* in_sizes, int n_in,
                              void* d_out, int out_size, void* d_ws, size_t ws_size,
                              hipStream_t stream) {
    const float* user_emb = (const float*)d_in[0];
    const float* item_emb = (const float*)d_in[1];
    const float* adj_vals = (const float*)d_in[2];
    const float* drop_u   = (const float*)d_in[3];
    const int*   adj_rows = (const int*)d_in[4];
    const int*   adj_cols = (const int*)d_in[5];
    const int*   users    = (const int*)d_in[6];
    const int*   pos_it   = (const int*)d_in[7];
    const int*   neg_it   = (const int*)d_in[8];
    const int*   u_a      = (const int*)d_in[9];
    const int*   p_a      = (const int*)d_in[10];
    const int*   n_a      = (const int*)d_in[11];
    const int*   indexp   = (const int*)d_in[12];
    float* out = (float*)d_out;

    // workspace layout (~78 MB)
    const size_t egoElems = (size_t)N_NODES_C * EMB_C;       // 9.6M
    h16*   egoH0     = (h16*)d_ws;                           // 19.2 MB
    h16*   bufA      = egoH0 + egoElems;                     // 19.2 MB
    h16*   bufB      = bufA + egoElems;                      // 19.2 MB
    int2*  ep        = (int2*)(bufB + egoElems);             // 9.6 MB (final CSR)
    int2*  ev        = ep + NNZ_C;                           // 9.6 MB (build tmp)
    int*   row_start = (int*)(ev + NNZ_C);                   // 600 KB (+sentinel)
    int*   cnt2      = row_start + N_NODES_C + 1;            // ~172 KB
    int*   base2     = cnt2 + N2 + 1;                        // ~172 KB
    int*   btot      = base2 + N2 + 1;                       // ~1.2 KB
    int*   bbase     = btot + NB + 1;                        // ~1.2 KB
    int*   flags     = bbase + NB + 1;                       // 600 KB

    // ---- CSR build: bucketed counting sort, all randomness L2-confined ----
    k_bin_count<<<NBLK, 1024, 0, stream>>>(drop_u, adj_rows, cnt2);
    k_btot<<<NB, 256, 0, stream>>>(cnt2, btot);
    k_bbase<<<1, 512, 0, stream>>>(btot, bbase, base2, row_start);
    k_bscan<<<NB, 256, 0, stream>>>(cnt2, bbase, base2);
    k_bin_write<<<NBLK, 1024, 0, stream>>>(adj_vals, drop_u, adj_rows, adj_cols,
                                           base2, ev);
    k_bucket_sort<<<NB, 256, 0, stream>>>(ev, base2, ep, row_start);

    // ---- hop-3 need-flags (after CSR is ready) ----
    hipMemsetAsync(flags, 0, N_NODES_C * sizeof(int), stream);
    k_flags<<<(3 * BATCH_C * 64 + 255) / 256, 256, 0, stream>>>(
        row_start, ep, flags, users, pos_it, neg_it, u_a, p_a, n_a, indexp);

    // ---- fp16 ego0 + hop-0 gather ----
    k_tohalf<<<2048, 256, 0, stream>>>((const float4*)user_emb,
                                       (const float4*)item_emb, (h16x4*)egoH0);
    const int GT = 3 * BATCH_C * EMB_C;
    k_gather<<<(GT + 255) / 256, 256, 0, stream>>>(user_emb, item_emb, N_USER_C, out,
                                                   users, pos_it, neg_it,
                                                   u_a, p_a, n_a, indexp);

    // ---- SpMM hops (fp16 ego, 8-slot waves); hop 3 flag-pruned; hop 4 fused ----
    const int SPMM_BLOCKS = (N_NODES_C * 64 + 255) / 256;    // one wave per row
    k_spmm8<<<SPMM_BLOCKS, 256, 0, stream>>>(row_start, ep, (const h16x8*)egoH0,
                                             (h16x8*)bufA, (const int*)nullptr);
    k_gather_h<<<(GT + 255) / 256, 256, 0, stream>>>(bufA, out, users, pos_it, neg_it,
                                                     u_a, p_a, n_a, indexp, 1);
    k_spmm8<<<SPMM_BLOCKS, 256, 0, stream>>>(row_start, ep, (const h16x8*)bufA,
                                             (h16x8*)bufB, (const int*)nullptr);
    k_gather_h<<<(GT + 255) / 256, 256, 0, stream>>>(bufB, out, users, pos_it, neg_it,
                                                     u_a, p_a, n_a, indexp, 2);
    k_spmm8<<<SPMM_BLOCKS, 256, 0, stream>>>(row_start, ep, (const h16x8*)bufB,
                                             (h16x8*)bufA, flags);
    k_gather_h<<<(GT + 255) / 256, 256, 0, stream>>>(bufA, out, users, pos_it, neg_it,
                                                     u_a, p_a, n_a, indexp, 3);
    k_spmm_g4<<<(3 * BATCH_C * 64 + 255) / 256, 256, 0, stream>>>(
        row_start, ep, (const h16x4*)bufA, out,
        users, pos_it, neg_it, u_a, p_a, n_a, indexp);

    // ---- final divide by (a+1) ----
    k_scale<<<(GT + 255) / 256, 256, 0, stream>>>(out, u_a, p_a, n_a);
}